// Round 4
// baseline (2406.747 us; speedup 1.0000x reference)
//
#include <hip/hip_runtime.h>
#include <hip/hip_bf16.h>
#include <math.h>

#define NN 100000      // nodes
#define NE 1600000     // edges
#define HD 64          // feature dim
#define NG 1000        // graphs
#define NC 10          // classes

#define NB 782         // buckets = ceil(NN/128), bucket = dst>>7 (128-node range)
#define NBLK 196       // partition blocks
#define EPB 8164       // edges per partition block = ceil(NE/NBLK)

// ---------------- pass 1a: per-block bucket histogram ----------------
__global__ __launch_bounds__(256) void hist_buckets(const int* __restrict__ dst,
                                                    int* __restrict__ hist)
{
    __shared__ int cnt[NB];
    int t = threadIdx.x, blk = blockIdx.x;
    for (int i = t; i < NB; i += 256) cnt[i] = 0;
    __syncthreads();
    int e0 = blk * EPB;
    int e1 = e0 + EPB; if (e1 > NE) e1 = NE;
    for (int e = e0 + t; e < e1; e += 256) atomicAdd(&cnt[dst[e] >> 7], 1);
    __syncthreads();
    for (int i = t; i < NB; i += 256) hist[(size_t)i * NBLK + blk] = cnt[i];
}

// ---------------- pass 1b: per-bucket totals ----------------
__global__ __launch_bounds__(256) void bucket_total(const int* __restrict__ hist,
                                                    int* __restrict__ btotal)
{
    int w = (blockIdx.x * 256 + threadIdx.x) >> 6;
    int lane = threadIdx.x & 63;
    if (w >= NB) return;
    const int* row = hist + (size_t)w * NBLK;
    int s = 0;
    for (int i = lane; i < NBLK; i += 64) s += row[i];
#pragma unroll
    for (int off = 32; off; off >>= 1) s += __shfl_xor(s, off);
    if (lane == 0) btotal[w] = s;
}

// ---------------- pass 1c: scan bucket totals -> bucketoff ----------------
__global__ __launch_bounds__(1024) void scan_totals(const int* __restrict__ btotal,
                                                    int* __restrict__ bucketoff)
{
    __shared__ int sm[1024];
    int t = threadIdx.x;
    int v = (t < NB) ? btotal[t] : 0;
    sm[t] = v;
    __syncthreads();
    for (int off = 1; off < 1024; off <<= 1) {
        int u = (t >= off) ? sm[t - off] : 0;
        __syncthreads();
        sm[t] += u;
        __syncthreads();
    }
    if (t <= NB) bucketoff[t] = sm[t] - ((t < NB) ? v : 0);
}

// ---------------- pass 1d: hist counts -> global write offsets (in place) ----------------
__global__ __launch_bounds__(256) void scan_hist(int* __restrict__ hist,
                                                 const int* __restrict__ bucketoff)
{
    int w = (blockIdx.x * 256 + threadIdx.x) >> 6;
    int lane = threadIdx.x & 63;
    if (w >= NB) return;
    int run = bucketoff[w];
    int* row = hist + (size_t)w * NBLK;
    for (int c0 = 0; c0 < NBLK; c0 += 64) {
        int idx = c0 + lane;
        int v = (idx < NBLK) ? row[idx] : 0;
        int incl = v;
#pragma unroll
        for (int off = 1; off < 64; off <<= 1) {
            int u = __shfl_up(incl, off);
            if (lane >= off) incl += u;
        }
        if (idx < NBLK) row[idx] = run + incl - v;
        run += __shfl(incl, 63);
    }
}

// ---------------- pass 2: bin edges -> packed pairs (row7|src17), grouped by bucket ----------------
__global__ __launch_bounds__(256) void bin_edges(const int* __restrict__ src,
                                                 const int* __restrict__ dst,
                                                 const int* __restrict__ hist,
                                                 unsigned* __restrict__ pairs)
{
    __shared__ int cur[NB];
    int t = threadIdx.x, blk = blockIdx.x;
    for (int i = t; i < NB; i += 256) cur[i] = hist[(size_t)i * NBLK + blk];
    __syncthreads();
    int e0 = blk * EPB;
    int e1 = e0 + EPB; if (e1 > NE) e1 = NE;
    for (int e = e0 + t; e < e1; e += 256) {
        int d = dst[e], s = src[e];
        int b = d >> 7;
        int pos = atomicAdd(&cur[b], 1);
        pairs[pos] = ((unsigned)(d & 127) << 17) | (unsigned)s;
    }
}

// ---------------- dinv from binned pairs ----------------
__global__ __launch_bounds__(256) void dinv_from_pairs(const int* __restrict__ bucketoff,
                                                       const unsigned* __restrict__ pairs,
                                                       float* __restrict__ dinv)
{
    __shared__ int cnt[128];
    int b = blockIdx.x, t = threadIdx.x;
    if (t < 128) cnt[t] = 0;
    __syncthreads();
    int e0 = bucketoff[b], e1 = bucketoff[b + 1];
    for (int e = e0 + t; e < e1; e += 256) atomicAdd(&cnt[pairs[e] >> 17], 1);
    __syncthreads();
    if (t < 128) {
        int node = b * 128 + t;
        if (node < NN) dinv[node] = rsqrtf((float)cnt[t] + 1.0f);
    }
}

// ---------------- per-layer GEMM: y = (h @ W^T) * dinv ----------------
__global__ __launch_bounds__(256) void gemm_scale(const float* __restrict__ h,
                                                  const float* __restrict__ W,
                                                  const float* __restrict__ dinv,
                                                  float* __restrict__ y,
                                                  int nrows)
{
    const int lane = threadIdx.x & 63;
    const int wave = threadIdx.x >> 6;

    float Wreg[64];
    const float4* Wv = (const float4*)(W + lane * 64);
#pragma unroll
    for (int k4 = 0; k4 < 16; ++k4) {
        float4 wv = Wv[k4];
        Wreg[k4 * 4 + 0] = wv.x; Wreg[k4 * 4 + 1] = wv.y;
        Wreg[k4 * 4 + 2] = wv.z; Wreg[k4 * 4 + 3] = wv.w;
    }

#pragma unroll 1
    for (int i = 0; i < 16; ++i) {
        int r = blockIdx.x * 64 + i * 4 + wave;
        if (r >= nrows) break;
        const float4* hrow = (const float4*)(h + r * 64);
        float a0 = 0.f, a1 = 0.f, a2 = 0.f, a3 = 0.f;
#pragma unroll
        for (int k4 = 0; k4 < 16; ++k4) {
            float4 hv = hrow[k4];            // wave-uniform broadcast load
            a0 = fmaf(hv.x, Wreg[k4 * 4 + 0], a0);
            a1 = fmaf(hv.y, Wreg[k4 * 4 + 1], a1);
            a2 = fmaf(hv.z, Wreg[k4 * 4 + 2], a2);
            a3 = fmaf(hv.w, Wreg[k4 * 4 + 3], a3);
        }
        float acc = (a0 + a1) + (a2 + a3);
        y[(size_t)r * 64 + lane] = acc * dinv[r];   // pre-scaled by dinv[src]
    }
}

// ---------------- tile aggregation: hout[n] = relu(dinv[n]*(y[n] + sum_in y[src]) + b) ----------------
__global__ __launch_bounds__(512) void aggr_tile(const int* __restrict__ bucketoff,
                                                 const unsigned* __restrict__ pairs,
                                                 const float* __restrict__ y,
                                                 const float* __restrict__ dinv,
                                                 const float* __restrict__ bias,
                                                 float* __restrict__ hout)
{
    __shared__ float tile[128 * 64];   // 32 KB
    int b = blockIdx.x;
    int lane = threadIdx.x & 63, wv = threadIdx.x >> 6;   // 8 waves
    int base = b << 7;
    int nrows = NN - base; if (nrows > 128) nrows = 128;

    for (int r = wv; r < nrows; r += 8)
        tile[r * 64 + lane] = y[(size_t)(base + r) * 64 + lane];   // self-loop term
    __syncthreads();

    int e0 = bucketoff[b], e1 = bucketoff[b + 1];
    for (int be = e0 + wv * 64; be < e1; be += 512) {
        int nb = e1 - be; if (nb > 64) nb = 64;
        unsigned pk = (lane < nb) ? pairs[be + lane] : 0u;   // coalesced batch
        int j = 0;
        for (; j + 8 <= nb; j += 8) {                        // 8 gathers in flight
            unsigned p0 = __shfl(pk, j + 0), p1 = __shfl(pk, j + 1);
            unsigned p2 = __shfl(pk, j + 2), p3 = __shfl(pk, j + 3);
            unsigned p4 = __shfl(pk, j + 4), p5 = __shfl(pk, j + 5);
            unsigned p6 = __shfl(pk, j + 6), p7 = __shfl(pk, j + 7);
            float v0 = y[(size_t)(p0 & 0x1FFFF) * 64 + lane];
            float v1 = y[(size_t)(p1 & 0x1FFFF) * 64 + lane];
            float v2 = y[(size_t)(p2 & 0x1FFFF) * 64 + lane];
            float v3 = y[(size_t)(p3 & 0x1FFFF) * 64 + lane];
            float v4 = y[(size_t)(p4 & 0x1FFFF) * 64 + lane];
            float v5 = y[(size_t)(p5 & 0x1FFFF) * 64 + lane];
            float v6 = y[(size_t)(p6 & 0x1FFFF) * 64 + lane];
            float v7 = y[(size_t)(p7 & 0x1FFFF) * 64 + lane];
            atomicAdd(&tile[(p0 >> 17) * 64 + lane], v0);
            atomicAdd(&tile[(p1 >> 17) * 64 + lane], v1);
            atomicAdd(&tile[(p2 >> 17) * 64 + lane], v2);
            atomicAdd(&tile[(p3 >> 17) * 64 + lane], v3);
            atomicAdd(&tile[(p4 >> 17) * 64 + lane], v4);
            atomicAdd(&tile[(p5 >> 17) * 64 + lane], v5);
            atomicAdd(&tile[(p6 >> 17) * 64 + lane], v6);
            atomicAdd(&tile[(p7 >> 17) * 64 + lane], v7);
        }
        for (; j < nb; ++j) {
            unsigned p = __shfl(pk, j);
            atomicAdd(&tile[(p >> 17) * 64 + lane], y[(size_t)(p & 0x1FFFF) * 64 + lane]);
        }
    }
    __syncthreads();

    for (int r = wv; r < nrows; r += 8) {
        int node = base + r;
        float v = fmaf(tile[r * 64 + lane], dinv[node], bias[lane]);
        hout[(size_t)node * 64 + lane] = fmaxf(v, 0.f);
    }
}

// ---------------- pool (mean per graph, batch sorted) + FFN + softmax ----------------
__global__ __launch_bounds__(64) void pool_ffn(const float* __restrict__ h3,
                                               const int* __restrict__ batch,
                                               const float* __restrict__ Wf,
                                               const float* __restrict__ bf,
                                               float* __restrict__ pooled,
                                               float* __restrict__ ffn,
                                               float* __restrict__ soft)
{
    int g = blockIdx.x;
    int lane = threadIdx.x;

    int lo = 0, hi = NN;
    while (lo < hi) { int mid = (lo + hi) >> 1; if (batch[mid] < g) lo = mid + 1; else hi = mid; }
    int start = lo;
    lo = start; hi = NN;
    while (lo < hi) { int mid = (lo + hi) >> 1; if (batch[mid] < g + 1) lo = mid + 1; else hi = mid; }
    int end = lo;

    float acc = 0.f;
    for (int n = start; n < end; ++n) acc += h3[(size_t)n * 64 + lane];
    float cnt = (float)(end - start);
    float pv = acc / fmaxf(cnt, 1.0f);
    pooled[g * 64 + lane] = pv;

    float f = 0.f;
#pragma unroll
    for (int cls = 0; cls < NC; ++cls) {
        float v = pv * Wf[cls * 64 + lane];
#pragma unroll
        for (int off = 32; off; off >>= 1) v += __shfl_xor(v, off);
        if (lane == cls) f = v;
    }
    float fb = (lane < NC) ? fmaxf(f + bf[lane], 0.f) : -INFINITY;
    if (lane < NC) ffn[g * NC + lane] = fb;

    float m = fb;
#pragma unroll
    for (int off = 32; off; off >>= 1) m = fmaxf(m, __shfl_xor(m, off));
    float e = (lane < NC) ? expf(fb - m) : 0.f;
    float s = e;
#pragma unroll
    for (int off = 32; off; off >>= 1) s += __shfl_xor(s, off);
    if (lane < NC) soft[g * NC + lane] = e / s;
}

extern "C" void kernel_launch(void* const* d_in, const int* in_sizes, int n_in,
                              void* d_out, int out_size, void* d_ws, size_t ws_size,
                              hipStream_t stream) {
    const float* x   = (const float*)d_in[0];
    const int*   ei  = (const int*)d_in[1];
    const int*   bat = (const int*)d_in[2];
    const float* W1  = (const float*)d_in[3];
    const float* b1  = (const float*)d_in[4];
    const float* W2  = (const float*)d_in[5];
    const float* b2  = (const float*)d_in[6];
    const float* W3  = (const float*)d_in[7];
    const float* b3  = (const float*)d_in[8];
    const float* Wf  = (const float*)d_in[9];
    const float* bf  = (const float*)d_in[10];

    const int* src = ei;
    const int* dst = ei + NE;

    float* out    = (float*)d_out;
    float* h1     = out;
    float* h2     = out + (size_t)NN * HD;
    float* h3     = out + (size_t)2 * NN * HD;
    float* pooled = out + (size_t)3 * NN * HD;
    float* ffn    = pooled + (size_t)NG * HD;
    float* soft   = ffn + (size_t)NG * NC;

    // workspace layout (bytes):
    //   dinv      [NN f32]          @ 0
    //   y         [NN*64 f32]       @ 400000
    //   pairs     [NE u32]          @ 26000000
    //   hist      [NB*NBLK i32]     @ 32400000  (782*196*4 = 613088)
    //   btotal    [NB i32]          @ 33013088
    //   bucketoff [NB+1 i32]        @ 33016216  (end 33019348 < 33.2MB proven)
    char* ws = (char*)d_ws;
    float*    dinv      = (float*)(ws + 0);
    float*    y         = (float*)(ws + 400000);
    unsigned* pairs     = (unsigned*)(ws + 26000000);
    int*      hist      = (int*)(ws + 32400000);
    int*      btotal    = (int*)(ws + 33013088);
    int*      bucketoff = (int*)(ws + 33016216);

    // ---- edge partition by dst bucket (amortized across all 3 layers) ----
    hist_buckets<<<NBLK, 256, 0, stream>>>(dst, hist);
    bucket_total<<<(NB + 3) / 4, 256, 0, stream>>>(hist, btotal);
    scan_totals<<<1, 1024, 0, stream>>>(btotal, bucketoff);
    scan_hist<<<(NB + 3) / 4, 256, 0, stream>>>(hist, bucketoff);
    bin_edges<<<NBLK, 256, 0, stream>>>(src, dst, hist, pairs);
    dinv_from_pairs<<<NB, 256, 0, stream>>>(bucketoff, pairs, dinv);

    const int gemmGrid = (NN + 63) / 64;

    gemm_scale<<<gemmGrid, 256, 0, stream>>>(x, W1, dinv, y, NN);
    aggr_tile<<<NB, 512, 0, stream>>>(bucketoff, pairs, y, dinv, b1, h1);

    gemm_scale<<<gemmGrid, 256, 0, stream>>>(h1, W2, dinv, y, NN);
    aggr_tile<<<NB, 512, 0, stream>>>(bucketoff, pairs, y, dinv, b2, h2);

    gemm_scale<<<gemmGrid, 256, 0, stream>>>(h2, W3, dinv, y, NN);
    aggr_tile<<<NB, 512, 0, stream>>>(bucketoff, pairs, y, dinv, b3, h3);

    pool_ffn<<<NG, 64, 0, stream>>>(h3, bat, Wf, bf, pooled, ffn, soft);
}

// Round 5
// 555.164 us; speedup vs baseline: 4.3352x; 4.3352x over previous
//
#include <hip/hip_runtime.h>
#include <hip/hip_bf16.h>
#include <math.h>

#define NN 100000      // nodes
#define NE 1600000     // edges
#define HD 64          // feature dim
#define NG 1000        // graphs
#define NC 10          // classes

#define NB 782         // buckets = ceil(NN/128), bucket = dst>>7 (128-node range)
#define NBLK 196       // partition blocks (keep ~10-edge runs per bucket -> low write-amp)
#define EPB 8164       // edges per partition block = ceil(NE/NBLK)

// ---------------- pass 1a: per-block bucket histogram ----------------
__global__ __launch_bounds__(256) void hist_buckets(const int* __restrict__ dst,
                                                    int* __restrict__ hist)
{
    __shared__ int cnt[NB];
    int t = threadIdx.x, blk = blockIdx.x;
    for (int i = t; i < NB; i += 256) cnt[i] = 0;
    __syncthreads();
    int e0 = blk * EPB;
    int e1 = e0 + EPB; if (e1 > NE) e1 = NE;
    for (int e = e0 + t; e < e1; e += 256) atomicAdd(&cnt[dst[e] >> 7], 1);
    __syncthreads();
    for (int i = t; i < NB; i += 256) hist[(size_t)i * NBLK + blk] = cnt[i];
}

// ---------------- pass 1b: per-bucket totals ----------------
__global__ __launch_bounds__(256) void bucket_total(const int* __restrict__ hist,
                                                    int* __restrict__ btotal)
{
    int w = (blockIdx.x * 256 + threadIdx.x) >> 6;
    int lane = threadIdx.x & 63;
    if (w >= NB) return;
    const int* row = hist + (size_t)w * NBLK;
    int s = 0;
    for (int i = lane; i < NBLK; i += 64) s += row[i];
#pragma unroll
    for (int off = 32; off; off >>= 1) s += __shfl_xor(s, off);
    if (lane == 0) btotal[w] = s;
}

// ---------------- pass 1c: scan bucket totals -> bucketoff ----------------
__global__ __launch_bounds__(1024) void scan_totals(const int* __restrict__ btotal,
                                                    int* __restrict__ bucketoff)
{
    __shared__ int sm[1024];
    int t = threadIdx.x;
    int v = (t < NB) ? btotal[t] : 0;
    sm[t] = v;
    __syncthreads();
    for (int off = 1; off < 1024; off <<= 1) {
        int u = (t >= off) ? sm[t - off] : 0;
        __syncthreads();
        sm[t] += u;
        __syncthreads();
    }
    if (t <= NB) bucketoff[t] = sm[t] - ((t < NB) ? v : 0);
}

// ---------------- pass 1d: hist counts -> global write offsets (in place) ----------------
__global__ __launch_bounds__(256) void scan_hist(int* __restrict__ hist,
                                                 const int* __restrict__ bucketoff)
{
    int w = (blockIdx.x * 256 + threadIdx.x) >> 6;
    int lane = threadIdx.x & 63;
    if (w >= NB) return;
    int run = bucketoff[w];
    int* row = hist + (size_t)w * NBLK;
    for (int c0 = 0; c0 < NBLK; c0 += 64) {
        int idx = c0 + lane;
        int v = (idx < NBLK) ? row[idx] : 0;
        int incl = v;
#pragma unroll
        for (int off = 1; off < 64; off <<= 1) {
            int u = __shfl_up(incl, off);
            if (lane >= off) incl += u;
        }
        if (idx < NBLK) row[idx] = run + incl - v;
        run += __shfl(incl, 63);
    }
}

// ---------------- pass 2: bin edges -> packed pairs (row7|src17), grouped by bucket ----------------
__global__ __launch_bounds__(256) void bin_edges(const int* __restrict__ src,
                                                 const int* __restrict__ dst,
                                                 const int* __restrict__ hist,
                                                 unsigned* __restrict__ pairs)
{
    __shared__ int cur[NB];
    int t = threadIdx.x, blk = blockIdx.x;
    for (int i = t; i < NB; i += 256) cur[i] = hist[(size_t)i * NBLK + blk];
    __syncthreads();
    int e0 = blk * EPB;
    int e1 = e0 + EPB; if (e1 > NE) e1 = NE;
    for (int e = e0 + t; e < e1; e += 256) {
        int d = dst[e], s = src[e];
        int b = d >> 7;
        int pos = atomicAdd(&cur[b], 1);
        pairs[pos] = ((unsigned)(d & 127) << 17) | (unsigned)s;
    }
}

// ---------------- pass 3: per-bucket counting sort -> srcidx (dst-sorted), rowstart, dinv ----------------
__global__ __launch_bounds__(256) void sort_bucket(const int* __restrict__ bucketoff,
                                                   const unsigned* __restrict__ pairs,
                                                   int* __restrict__ rowstart,
                                                   int* __restrict__ srcidx,
                                                   float* __restrict__ dinv)
{
    __shared__ int cnt[128], off[128], cur[128];
    int b = blockIdx.x, t = threadIdx.x;
    int e0 = bucketoff[b], e1 = bucketoff[b + 1];
    if (t < 128) cnt[t] = 0;
    __syncthreads();
    for (int e = e0 + t; e < e1; e += 256) atomicAdd(&cnt[pairs[e] >> 17], 1);
    __syncthreads();
    if (t < 128) off[t] = cnt[t];
    __syncthreads();
    for (int o = 1; o < 128; o <<= 1) {           // Hillis-Steele inclusive scan
        int u = (t < 128 && t >= o) ? off[t - o] : 0;
        __syncthreads();
        if (t < 128) off[t] += u;
        __syncthreads();
    }
    if (t < 128) {
        int ex = e0 + off[t] - cnt[t];            // exclusive + bucket base
        cur[t] = ex;
        int node = (b << 7) + t;
        if (node < NN) {
            rowstart[node] = ex;
            dinv[node] = rsqrtf((float)cnt[t] + 1.0f);
        }
    }
    if (b == NB - 1 && t == 0) rowstart[NN] = e1; // == NE
    __syncthreads();
    for (int e = e0 + t; e < e1; e += 256) {
        unsigned pk = pairs[e];
        int pos = atomicAdd(&cur[pk >> 17], 1);
        srcidx[pos] = (int)(pk & 0x1FFFF);        // block-local contiguous region
    }
}

// ---------------- per-layer GEMM: y = (h @ W^T) * dinv ----------------
__global__ __launch_bounds__(256) void gemm_scale(const float* __restrict__ h,
                                                  const float* __restrict__ W,
                                                  const float* __restrict__ dinv,
                                                  float* __restrict__ y,
                                                  int nrows)
{
    const int lane = threadIdx.x & 63;
    const int wave = threadIdx.x >> 6;

    float Wreg[64];
    const float4* Wv = (const float4*)(W + lane * 64);
#pragma unroll
    for (int k4 = 0; k4 < 16; ++k4) {
        float4 wv = Wv[k4];
        Wreg[k4 * 4 + 0] = wv.x; Wreg[k4 * 4 + 1] = wv.y;
        Wreg[k4 * 4 + 2] = wv.z; Wreg[k4 * 4 + 3] = wv.w;
    }

#pragma unroll 1
    for (int i = 0; i < 16; ++i) {
        int r = blockIdx.x * 64 + i * 4 + wave;
        if (r >= nrows) break;
        const float4* hrow = (const float4*)(h + r * 64);
        float a0 = 0.f, a1 = 0.f, a2 = 0.f, a3 = 0.f;
#pragma unroll
        for (int k4 = 0; k4 < 16; ++k4) {
            float4 hv = hrow[k4];            // wave-uniform broadcast load
            a0 = fmaf(hv.x, Wreg[k4 * 4 + 0], a0);
            a1 = fmaf(hv.y, Wreg[k4 * 4 + 1], a1);
            a2 = fmaf(hv.z, Wreg[k4 * 4 + 2], a2);
            a3 = fmaf(hv.w, Wreg[k4 * 4 + 3], a3);
        }
        float acc = (a0 + a1) + (a2 + a3);
        y[(size_t)r * 64 + lane] = acc * dinv[r];   // pre-scaled by dinv[src]
    }
}

// ---------------- pull aggregation: h[n] = relu((y[n] + sum_in y[src]) * dinv[n] + b) ----------------
__global__ __launch_bounds__(256) void pull_aggr(const int* __restrict__ rowstart,
                                                 const int* __restrict__ srcidx,
                                                 const float* __restrict__ y,
                                                 const float* __restrict__ dinv,
                                                 const float* __restrict__ bias,
                                                 float* __restrict__ hout)
{
    int wid = (blockIdx.x * blockDim.x + threadIdx.x) >> 6;
    int lane = threadIdx.x & 63;
    if (wid >= NN) return;
    int s0 = rowstart[wid], s1 = rowstart[wid + 1];
    float acc = y[(size_t)wid * 64 + lane];          // self-loop term (y = xw*dinv)
    for (int base = s0; base < s1; base += 64) {
        int nb = s1 - base; if (nb > 64) nb = 64;
        int idx = (lane < nb) ? srcidx[base + lane] : 0;   // coalesced batch of indices
        int j = 0;
        for (; j + 4 <= nb; j += 4) {                 // 4 independent gathers in flight
            int i0 = __shfl(idx, j + 0), i1 = __shfl(idx, j + 1);
            int i2 = __shfl(idx, j + 2), i3 = __shfl(idx, j + 3);
            float v0 = y[(size_t)i0 * 64 + lane];
            float v1 = y[(size_t)i1 * 64 + lane];
            float v2 = y[(size_t)i2 * 64 + lane];
            float v3 = y[(size_t)i3 * 64 + lane];
            acc += v0; acc += v1; acc += v2; acc += v3;
        }
        for (; j < nb; ++j) {
            int s = __shfl(idx, j);
            acc += y[(size_t)s * 64 + lane];
        }
    }
    float v = fmaf(acc, dinv[wid], bias[lane]);
    hout[(size_t)wid * 64 + lane] = fmaxf(v, 0.f);
}

// ---------------- pool (mean per graph, batch sorted) + FFN + softmax ----------------
__global__ __launch_bounds__(64) void pool_ffn(const float* __restrict__ h3,
                                               const int* __restrict__ batch,
                                               const float* __restrict__ Wf,
                                               const float* __restrict__ bf,
                                               float* __restrict__ pooled,
                                               float* __restrict__ ffn,
                                               float* __restrict__ soft)
{
    int g = blockIdx.x;
    int lane = threadIdx.x;

    int lo = 0, hi = NN;
    while (lo < hi) { int mid = (lo + hi) >> 1; if (batch[mid] < g) lo = mid + 1; else hi = mid; }
    int start = lo;
    lo = start; hi = NN;
    while (lo < hi) { int mid = (lo + hi) >> 1; if (batch[mid] < g + 1) lo = mid + 1; else hi = mid; }
    int end = lo;

    float acc = 0.f;
    for (int n = start; n < end; ++n) acc += h3[(size_t)n * 64 + lane];
    float cnt = (float)(end - start);
    float pv = acc / fmaxf(cnt, 1.0f);
    pooled[g * 64 + lane] = pv;

    float f = 0.f;
#pragma unroll
    for (int cls = 0; cls < NC; ++cls) {
        float v = pv * Wf[cls * 64 + lane];
#pragma unroll
        for (int off = 32; off; off >>= 1) v += __shfl_xor(v, off);
        if (lane == cls) f = v;
    }
    float fb = (lane < NC) ? fmaxf(f + bf[lane], 0.f) : -INFINITY;
    if (lane < NC) ffn[g * NC + lane] = fb;

    float m = fb;
#pragma unroll
    for (int off = 32; off; off >>= 1) m = fmaxf(m, __shfl_xor(m, off));
    float e = (lane < NC) ? expf(fb - m) : 0.f;
    float s = e;
#pragma unroll
    for (int off = 32; off; off >>= 1) s += __shfl_xor(s, off);
    if (lane < NC) soft[g * NC + lane] = e / s;
}

extern "C" void kernel_launch(void* const* d_in, const int* in_sizes, int n_in,
                              void* d_out, int out_size, void* d_ws, size_t ws_size,
                              hipStream_t stream) {
    const float* x   = (const float*)d_in[0];
    const int*   ei  = (const int*)d_in[1];
    const int*   bat = (const int*)d_in[2];
    const float* W1  = (const float*)d_in[3];
    const float* b1  = (const float*)d_in[4];
    const float* W2  = (const float*)d_in[5];
    const float* b2  = (const float*)d_in[6];
    const float* W3  = (const float*)d_in[7];
    const float* b3  = (const float*)d_in[8];
    const float* Wf  = (const float*)d_in[9];
    const float* bf  = (const float*)d_in[10];

    const int* src = ei;
    const int* dst = ei + NE;

    float* out    = (float*)d_out;
    float* h1     = out;
    float* h2     = out + (size_t)NN * HD;
    float* h3     = out + (size_t)2 * NN * HD;
    float* pooled = out + (size_t)3 * NN * HD;
    float* ffn    = pooled + (size_t)NG * HD;
    float* soft   = ffn + (size_t)NG * NC;

    // workspace layout (bytes), peak 32,800,016 (< 33.02 MB proven in R4):
    //   dinv      [NN f32]        @ 0
    //   rowstart  [NN+1 i32]      @ 400000
    //   srcidx    [NE i32]        @ 800016          (ends 7,200,016)
    //   y         [NN*64 f32]     @ 7200016         (ends 32,800,016; 16B aligned)
    //   -- partition temporaries overlap y (dead before first gemm writes y):
    //   pairs     [NE u32]        @ 7200016         (ends 13,600,016)
    //   hist      [NB*NBLK i32]   @ 13600016        (613,088 B)
    //   btotal    [NB i32]        @ 14213104
    //   bucketoff [NB+1 i32]      @ 14216232
    char* ws = (char*)d_ws;
    float*    dinv      = (float*)(ws + 0);
    int*      rowstart  = (int*)(ws + 400000);
    int*      srcidx    = (int*)(ws + 800016);
    float*    y         = (float*)(ws + 7200016);
    unsigned* pairs     = (unsigned*)(ws + 7200016);
    int*      hist      = (int*)(ws + 13600016);
    int*      btotal    = (int*)(ws + 14213104);
    int*      bucketoff = (int*)(ws + 14216232);

    // ---- edge partition + per-bucket counting sort (amortized across 3 layers) ----
    hist_buckets<<<NBLK, 256, 0, stream>>>(dst, hist);
    bucket_total<<<(NB + 3) / 4, 256, 0, stream>>>(hist, btotal);
    scan_totals<<<1, 1024, 0, stream>>>(btotal, bucketoff);
    scan_hist<<<(NB + 3) / 4, 256, 0, stream>>>(hist, bucketoff);
    bin_edges<<<NBLK, 256, 0, stream>>>(src, dst, hist, pairs);
    sort_bucket<<<NB, 256, 0, stream>>>(bucketoff, pairs, rowstart, srcidx, dinv);

    const int gemmGrid = (NN + 63) / 64;
    const int aggrGrid = (NN + 3) / 4;      // 4 waves (nodes) per 256-block

    gemm_scale<<<gemmGrid, 256, 0, stream>>>(x, W1, dinv, y, NN);
    pull_aggr<<<aggrGrid, 256, 0, stream>>>(rowstart, srcidx, y, dinv, b1, h1);

    gemm_scale<<<gemmGrid, 256, 0, stream>>>(h1, W2, dinv, y, NN);
    pull_aggr<<<aggrGrid, 256, 0, stream>>>(rowstart, srcidx, y, dinv, b2, h2);

    gemm_scale<<<gemmGrid, 256, 0, stream>>>(h2, W3, dinv, y, NN);
    pull_aggr<<<aggrGrid, 256, 0, stream>>>(rowstart, srcidx, y, dinv, b3, h3);

    pool_ffn<<<NG, 64, 0, stream>>>(h3, bat, Wf, bf, pooled, ffn, soft);
}

// Round 6
// 477.892 us; speedup vs baseline: 5.0362x; 1.1617x over previous
//
#include <hip/hip_runtime.h>
#include <hip/hip_bf16.h>
#include <math.h>

#define NN 100000      // nodes
#define NE 1600000     // edges
#define HD 64          // feature dim
#define NG 1000        // graphs
#define NC 10          // classes

#define NB 782         // buckets = ceil(NN/128), bucket = dst>>7 (128-node range)
#define NBLK 196       // partition blocks (keep ~10-edge runs per bucket -> low write-amp)
#define EPB 8164       // edges per partition block = ceil(NE/NBLK)

// ---------------- pass 1a: per-block bucket histogram ----------------
__global__ __launch_bounds__(256) void hist_buckets(const int* __restrict__ dst,
                                                    int* __restrict__ hist)
{
    __shared__ int cnt[NB];
    int t = threadIdx.x, blk = blockIdx.x;
    for (int i = t; i < NB; i += 256) cnt[i] = 0;
    __syncthreads();
    int e0 = blk * EPB;
    int e1 = e0 + EPB; if (e1 > NE) e1 = NE;
    for (int e = e0 + t; e < e1; e += 256) atomicAdd(&cnt[dst[e] >> 7], 1);
    __syncthreads();
    for (int i = t; i < NB; i += 256) hist[(size_t)i * NBLK + blk] = cnt[i];
}

// ---------------- pass 1b: per-bucket totals ----------------
__global__ __launch_bounds__(256) void bucket_total(const int* __restrict__ hist,
                                                    int* __restrict__ btotal)
{
    int w = (blockIdx.x * 256 + threadIdx.x) >> 6;
    int lane = threadIdx.x & 63;
    if (w >= NB) return;
    const int* row = hist + (size_t)w * NBLK;
    int s = 0;
    for (int i = lane; i < NBLK; i += 64) s += row[i];
#pragma unroll
    for (int off = 32; off; off >>= 1) s += __shfl_xor(s, off);
    if (lane == 0) btotal[w] = s;
}

// ---------------- pass 1c: scan bucket totals -> bucketoff ----------------
__global__ __launch_bounds__(1024) void scan_totals(const int* __restrict__ btotal,
                                                    int* __restrict__ bucketoff)
{
    __shared__ int sm[1024];
    int t = threadIdx.x;
    int v = (t < NB) ? btotal[t] : 0;
    sm[t] = v;
    __syncthreads();
    for (int off = 1; off < 1024; off <<= 1) {
        int u = (t >= off) ? sm[t - off] : 0;
        __syncthreads();
        sm[t] += u;
        __syncthreads();
    }
    if (t <= NB) bucketoff[t] = sm[t] - ((t < NB) ? v : 0);
}

// ---------------- pass 1d: hist counts -> global write offsets (in place) ----------------
__global__ __launch_bounds__(256) void scan_hist(int* __restrict__ hist,
                                                 const int* __restrict__ bucketoff)
{
    int w = (blockIdx.x * 256 + threadIdx.x) >> 6;
    int lane = threadIdx.x & 63;
    if (w >= NB) return;
    int run = bucketoff[w];
    int* row = hist + (size_t)w * NBLK;
    for (int c0 = 0; c0 < NBLK; c0 += 64) {
        int idx = c0 + lane;
        int v = (idx < NBLK) ? row[idx] : 0;
        int incl = v;
#pragma unroll
        for (int off = 1; off < 64; off <<= 1) {
            int u = __shfl_up(incl, off);
            if (lane >= off) incl += u;
        }
        if (idx < NBLK) row[idx] = run + incl - v;
        run += __shfl(incl, 63);
    }
}

// ---------------- pass 2: bin edges -> packed pairs (row7|src17), grouped by bucket ----------------
__global__ __launch_bounds__(256) void bin_edges(const int* __restrict__ src,
                                                 const int* __restrict__ dst,
                                                 const int* __restrict__ hist,
                                                 unsigned* __restrict__ pairs)
{
    __shared__ int cur[NB];
    int t = threadIdx.x, blk = blockIdx.x;
    for (int i = t; i < NB; i += 256) cur[i] = hist[(size_t)i * NBLK + blk];
    __syncthreads();
    int e0 = blk * EPB;
    int e1 = e0 + EPB; if (e1 > NE) e1 = NE;
    for (int e = e0 + t; e < e1; e += 256) {
        int d = dst[e], s = src[e];
        int b = d >> 7;
        int pos = atomicAdd(&cur[b], 1);
        pairs[pos] = ((unsigned)(d & 127) << 17) | (unsigned)s;
    }
}

// ---------------- pass 3: per-bucket counting sort -> srcidx (dst-sorted), rowstart, dinv ----------------
__global__ __launch_bounds__(256) void sort_bucket(const int* __restrict__ bucketoff,
                                                   const unsigned* __restrict__ pairs,
                                                   int* __restrict__ rowstart,
                                                   int* __restrict__ srcidx,
                                                   float* __restrict__ dinv)
{
    __shared__ int cnt[128], off[128], cur[128];
    int b = blockIdx.x, t = threadIdx.x;
    int e0 = bucketoff[b], e1 = bucketoff[b + 1];
    if (t < 128) cnt[t] = 0;
    __syncthreads();
    for (int e = e0 + t; e < e1; e += 256) atomicAdd(&cnt[pairs[e] >> 17], 1);
    __syncthreads();
    if (t < 128) off[t] = cnt[t];
    __syncthreads();
    for (int o = 1; o < 128; o <<= 1) {           // Hillis-Steele inclusive scan
        int u = (t < 128 && t >= o) ? off[t - o] : 0;
        __syncthreads();
        if (t < 128) off[t] += u;
        __syncthreads();
    }
    if (t < 128) {
        int ex = e0 + off[t] - cnt[t];            // exclusive + bucket base
        cur[t] = ex;
        int node = (b << 7) + t;
        if (node < NN) {
            rowstart[node] = ex;
            dinv[node] = rsqrtf((float)cnt[t] + 1.0f);
        }
    }
    if (b == NB - 1 && t == 0) rowstart[NN] = e1; // == NE
    __syncthreads();
    for (int e = e0 + t; e < e1; e += 256) {
        unsigned pk = pairs[e];
        int pos = atomicAdd(&cur[pk >> 17], 1);
        srcidx[pos] = (int)(pk & 0x1FFFF);        // block-local contiguous region
    }
}

// ---------------- per-layer GEMM: y = (h @ W^T) * dinv ----------------
// LDS-staged h tile: coalesced independent global loads, broadcast ds_reads.
__global__ __launch_bounds__(256) void gemm_scale(const float* __restrict__ h,
                                                  const float* __restrict__ W,
                                                  const float* __restrict__ dinv,
                                                  float* __restrict__ y,
                                                  int nrows)
{
    __shared__ float hs[64 * 64];   // 16 KB tile
    const int t = threadIdx.x;
    const int lane = t & 63;
    const int wave = t >> 6;
    const int rbase = blockIdx.x * 64;
    const int valid = (nrows - rbase < 64) ? (nrows - rbase) : 64;

    // W[lane][:] into registers (L2-resident, amortized over 16 rows)
    float Wreg[64];
    const float4* Wv = (const float4*)(W + lane * 64);
#pragma unroll
    for (int k4 = 0; k4 < 16; ++k4) {
        float4 wv = Wv[k4];
        Wreg[k4 * 4 + 0] = wv.x; Wreg[k4 * 4 + 1] = wv.y;
        Wreg[k4 * 4 + 2] = wv.z; Wreg[k4 * 4 + 3] = wv.w;
    }

    // stage 64 rows coalesced: 1024 float4, 4 per thread, all independent
    const float4* hg = (const float4*)(h + (size_t)rbase * 64);
    float4* hsv = (float4*)hs;
#pragma unroll
    for (int j = 0; j < 4; ++j) {
        int f = t + j * 256;
        if ((f >> 4) < valid) hsv[f] = hg[f];
    }
    __syncthreads();

#pragma unroll 1
    for (int i = 0; i < 16; ++i) {
        int r = i * 4 + wave;               // interleaved: balanced in partial blocks
        if (r >= valid) break;
        const float4* hrow = (const float4*)(hs + r * 64);
        float a0 = 0.f, a1 = 0.f, a2 = 0.f, a3 = 0.f;
#pragma unroll
        for (int k4 = 0; k4 < 16; ++k4) {
            float4 hv = hrow[k4];           // LDS broadcast read (conflict-free)
            a0 = fmaf(hv.x, Wreg[k4 * 4 + 0], a0);
            a1 = fmaf(hv.y, Wreg[k4 * 4 + 1], a1);
            a2 = fmaf(hv.z, Wreg[k4 * 4 + 2], a2);
            a3 = fmaf(hv.w, Wreg[k4 * 4 + 3], a3);
        }
        int rg = rbase + r;
        y[(size_t)rg * 64 + lane] = ((a0 + a1) + (a2 + a3)) * dinv[rg];
    }
}

// ---------------- pull aggregation: h[n] = relu((y[n] + sum_in y[src]) * dinv[n] + b) ----------------
__global__ __launch_bounds__(256) void pull_aggr(const int* __restrict__ rowstart,
                                                 const int* __restrict__ srcidx,
                                                 const float* __restrict__ y,
                                                 const float* __restrict__ dinv,
                                                 const float* __restrict__ bias,
                                                 float* __restrict__ hout)
{
    int wid = (blockIdx.x * blockDim.x + threadIdx.x) >> 6;
    int lane = threadIdx.x & 63;
    if (wid >= NN) return;
    int s0 = rowstart[wid], s1 = rowstart[wid + 1];
    float acc = y[(size_t)wid * 64 + lane];          // self-loop term (y = xw*dinv)
    for (int base = s0; base < s1; base += 64) {
        int nb = s1 - base; if (nb > 64) nb = 64;
        int idx = (lane < nb) ? srcidx[base + lane] : 0;   // coalesced batch of indices
        int j = 0;
        for (; j + 4 <= nb; j += 4) {                 // 4 independent gathers in flight
            int i0 = __shfl(idx, j + 0), i1 = __shfl(idx, j + 1);
            int i2 = __shfl(idx, j + 2), i3 = __shfl(idx, j + 3);
            float v0 = y[(size_t)i0 * 64 + lane];
            float v1 = y[(size_t)i1 * 64 + lane];
            float v2 = y[(size_t)i2 * 64 + lane];
            float v3 = y[(size_t)i3 * 64 + lane];
            acc += v0; acc += v1; acc += v2; acc += v3;
        }
        for (; j < nb; ++j) {
            int s = __shfl(idx, j);
            acc += y[(size_t)s * 64 + lane];
        }
    }
    float v = fmaf(acc, dinv[wid], bias[lane]);
    hout[(size_t)wid * 64 + lane] = fmaxf(v, 0.f);
}

// ---------------- pool (mean per graph, batch sorted) + FFN + softmax ----------------
__global__ __launch_bounds__(64) void pool_ffn(const float* __restrict__ h3,
                                               const int* __restrict__ batch,
                                               const float* __restrict__ Wf,
                                               const float* __restrict__ bf,
                                               float* __restrict__ pooled,
                                               float* __restrict__ ffn,
                                               float* __restrict__ soft)
{
    int g = blockIdx.x;
    int lane = threadIdx.x;

    int lo = 0, hi = NN;
    while (lo < hi) { int mid = (lo + hi) >> 1; if (batch[mid] < g) lo = mid + 1; else hi = mid; }
    int start = lo;
    lo = start; hi = NN;
    while (lo < hi) { int mid = (lo + hi) >> 1; if (batch[mid] < g + 1) lo = mid + 1; else hi = mid; }
    int end = lo;

    float acc = 0.f;
    for (int n = start; n < end; ++n) acc += h3[(size_t)n * 64 + lane];
    float cnt = (float)(end - start);
    float pv = acc / fmaxf(cnt, 1.0f);
    pooled[g * 64 + lane] = pv;

    float f = 0.f;
#pragma unroll
    for (int cls = 0; cls < NC; ++cls) {
        float v = pv * Wf[cls * 64 + lane];
#pragma unroll
        for (int off = 32; off; off >>= 1) v += __shfl_xor(v, off);
        if (lane == cls) f = v;
    }
    float fb = (lane < NC) ? fmaxf(f + bf[lane], 0.f) : -INFINITY;
    if (lane < NC) ffn[g * NC + lane] = fb;

    float m = fb;
#pragma unroll
    for (int off = 32; off; off >>= 1) m = fmaxf(m, __shfl_xor(m, off));
    float e = (lane < NC) ? expf(fb - m) : 0.f;
    float s = e;
#pragma unroll
    for (int off = 32; off; off >>= 1) s += __shfl_xor(s, off);
    if (lane < NC) soft[g * NC + lane] = e / s;
}

extern "C" void kernel_launch(void* const* d_in, const int* in_sizes, int n_in,
                              void* d_out, int out_size, void* d_ws, size_t ws_size,
                              hipStream_t stream) {
    const float* x   = (const float*)d_in[0];
    const int*   ei  = (const int*)d_in[1];
    const int*   bat = (const int*)d_in[2];
    const float* W1  = (const float*)d_in[3];
    const float* b1  = (const float*)d_in[4];
    const float* W2  = (const float*)d_in[5];
    const float* b2  = (const float*)d_in[6];
    const float* W3  = (const float*)d_in[7];
    const float* b3  = (const float*)d_in[8];
    const float* Wf  = (const float*)d_in[9];
    const float* bf  = (const float*)d_in[10];

    const int* src = ei;
    const int* dst = ei + NE;

    float* out    = (float*)d_out;
    float* h1     = out;
    float* h2     = out + (size_t)NN * HD;
    float* h3     = out + (size_t)2 * NN * HD;
    float* pooled = out + (size_t)3 * NN * HD;
    float* ffn    = pooled + (size_t)NG * HD;
    float* soft   = ffn + (size_t)NG * NC;

    // workspace layout (bytes), peak 32,800,016:
    //   dinv      [NN f32]        @ 0
    //   rowstart  [NN+1 i32]      @ 400000
    //   srcidx    [NE i32]        @ 800016          (ends 7,200,016)
    //   y         [NN*64 f32]     @ 7200016         (ends 32,800,016; 16B aligned)
    //   -- partition temporaries overlap y (dead before first gemm writes y):
    //   pairs     [NE u32]        @ 7200016         (ends 13,600,016)
    //   hist      [NB*NBLK i32]   @ 13600016        (613,088 B)
    //   btotal    [NB i32]        @ 14213104
    //   bucketoff [NB+1 i32]      @ 14216232
    char* ws = (char*)d_ws;
    float*    dinv      = (float*)(ws + 0);
    int*      rowstart  = (int*)(ws + 400000);
    int*      srcidx    = (int*)(ws + 800016);
    float*    y         = (float*)(ws + 7200016);
    unsigned* pairs     = (unsigned*)(ws + 7200016);
    int*      hist      = (int*)(ws + 13600016);
    int*      btotal    = (int*)(ws + 14213104);
    int*      bucketoff = (int*)(ws + 14216232);

    // ---- edge partition + per-bucket counting sort (amortized across 3 layers) ----
    hist_buckets<<<NBLK, 256, 0, stream>>>(dst, hist);
    bucket_total<<<(NB + 3) / 4, 256, 0, stream>>>(hist, btotal);
    scan_totals<<<1, 1024, 0, stream>>>(btotal, bucketoff);
    scan_hist<<<(NB + 3) / 4, 256, 0, stream>>>(hist, bucketoff);
    bin_edges<<<NBLK, 256, 0, stream>>>(src, dst, hist, pairs);
    sort_bucket<<<NB, 256, 0, stream>>>(bucketoff, pairs, rowstart, srcidx, dinv);

    const int gemmGrid = (NN + 63) / 64;
    const int aggrGrid = (NN + 3) / 4;      // 4 waves (nodes) per 256-block

    gemm_scale<<<gemmGrid, 256, 0, stream>>>(x, W1, dinv, y, NN);
    pull_aggr<<<aggrGrid, 256, 0, stream>>>(rowstart, srcidx, y, dinv, b1, h1);

    gemm_scale<<<gemmGrid, 256, 0, stream>>>(h1, W2, dinv, y, NN);
    pull_aggr<<<aggrGrid, 256, 0, stream>>>(rowstart, srcidx, y, dinv, b2, h2);

    gemm_scale<<<gemmGrid, 256, 0, stream>>>(h2, W3, dinv, y, NN);
    pull_aggr<<<aggrGrid, 256, 0, stream>>>(rowstart, srcidx, y, dinv, b3, h3);

    pool_ffn<<<NG, 64, 0, stream>>>(h3, bat, Wf, bf, pooled, ffn, soft);
}

// Round 7
// 410.042 us; speedup vs baseline: 5.8695x; 1.1655x over previous
//
#include <hip/hip_runtime.h>
#include <hip/hip_bf16.h>
#include <math.h>

#define NN 100000      // nodes
#define NE 1600000     // edges
#define HD 64          // feature dim
#define NG 1000        // graphs
#define NC 10          // classes

#define NB 782         // buckets = ceil(NN/128), bucket = dst>>7 (128-node range)
#define NBLK 196       // partition blocks (keep ~10-edge runs per bucket -> low write-amp)
#define EPB 8164       // edges per partition block = ceil(NE/NBLK)

__device__ __forceinline__ unsigned short f32_to_bf16(float f) {
    union { float f; unsigned u; } c; c.f = f;
    unsigned u = c.u;
    u += 0x7FFFu + ((u >> 16) & 1u);   // round-to-nearest-even
    return (unsigned short)(u >> 16);
}
__device__ __forceinline__ float bf16_to_f32(unsigned short h) {
    union { unsigned u; float f; } c; c.u = ((unsigned)h) << 16;
    return c.f;
}

// ---------------- pass 1a: per-block bucket histogram ----------------
__global__ __launch_bounds__(256) void hist_buckets(const int* __restrict__ dst,
                                                    int* __restrict__ hist)
{
    __shared__ int cnt[NB];
    int t = threadIdx.x, blk = blockIdx.x;
    for (int i = t; i < NB; i += 256) cnt[i] = 0;
    __syncthreads();
    int e0 = blk * EPB;
    int e1 = e0 + EPB; if (e1 > NE) e1 = NE;
    for (int e = e0 + t; e < e1; e += 256) atomicAdd(&cnt[dst[e] >> 7], 1);
    __syncthreads();
    for (int i = t; i < NB; i += 256) hist[(size_t)i * NBLK + blk] = cnt[i];
}

// ---------------- pass 1b: per-bucket totals ----------------
__global__ __launch_bounds__(256) void bucket_total(const int* __restrict__ hist,
                                                    int* __restrict__ btotal)
{
    int w = (blockIdx.x * 256 + threadIdx.x) >> 6;
    int lane = threadIdx.x & 63;
    if (w >= NB) return;
    const int* row = hist + (size_t)w * NBLK;
    int s = 0;
    for (int i = lane; i < NBLK; i += 64) s += row[i];
#pragma unroll
    for (int off = 32; off; off >>= 1) s += __shfl_xor(s, off);
    if (lane == 0) btotal[w] = s;
}

// ---------------- pass 1c: scan bucket totals -> bucketoff ----------------
__global__ __launch_bounds__(1024) void scan_totals(const int* __restrict__ btotal,
                                                    int* __restrict__ bucketoff)
{
    __shared__ int sm[1024];
    int t = threadIdx.x;
    int v = (t < NB) ? btotal[t] : 0;
    sm[t] = v;
    __syncthreads();
    for (int off = 1; off < 1024; off <<= 1) {
        int u = (t >= off) ? sm[t - off] : 0;
        __syncthreads();
        sm[t] += u;
        __syncthreads();
    }
    if (t <= NB) bucketoff[t] = sm[t] - ((t < NB) ? v : 0);
}

// ---------------- pass 1d: hist counts -> global write offsets (in place) ----------------
__global__ __launch_bounds__(256) void scan_hist(int* __restrict__ hist,
                                                 const int* __restrict__ bucketoff)
{
    int w = (blockIdx.x * 256 + threadIdx.x) >> 6;
    int lane = threadIdx.x & 63;
    if (w >= NB) return;
    int run = bucketoff[w];
    int* row = hist + (size_t)w * NBLK;
    for (int c0 = 0; c0 < NBLK; c0 += 64) {
        int idx = c0 + lane;
        int v = (idx < NBLK) ? row[idx] : 0;
        int incl = v;
#pragma unroll
        for (int off = 1; off < 64; off <<= 1) {
            int u = __shfl_up(incl, off);
            if (lane >= off) incl += u;
        }
        if (idx < NBLK) row[idx] = run + incl - v;
        run += __shfl(incl, 63);
    }
}

// ---------------- pass 2: bin edges -> packed pairs (row7|src17), grouped by bucket ----------------
__global__ __launch_bounds__(256) void bin_edges(const int* __restrict__ src,
                                                 const int* __restrict__ dst,
                                                 const int* __restrict__ hist,
                                                 unsigned* __restrict__ pairs)
{
    __shared__ int cur[NB];
    int t = threadIdx.x, blk = blockIdx.x;
    for (int i = t; i < NB; i += 256) cur[i] = hist[(size_t)i * NBLK + blk];
    __syncthreads();
    int e0 = blk * EPB;
    int e1 = e0 + EPB; if (e1 > NE) e1 = NE;
    for (int e = e0 + t; e < e1; e += 256) {
        int d = dst[e], s = src[e];
        int b = d >> 7;
        int pos = atomicAdd(&cur[b], 1);
        pairs[pos] = ((unsigned)(d & 127) << 17) | (unsigned)s;
    }
}

// ---------------- pass 3: per-bucket counting sort -> srcidx (dst-sorted), rowstart, dinv ----------------
__global__ __launch_bounds__(256) void sort_bucket(const int* __restrict__ bucketoff,
                                                   const unsigned* __restrict__ pairs,
                                                   int* __restrict__ rowstart,
                                                   int* __restrict__ srcidx,
                                                   float* __restrict__ dinv)
{
    __shared__ int cnt[128], off[128], cur[128];
    int b = blockIdx.x, t = threadIdx.x;
    int e0 = bucketoff[b], e1 = bucketoff[b + 1];
    if (t < 128) cnt[t] = 0;
    __syncthreads();
    for (int e = e0 + t; e < e1; e += 256) atomicAdd(&cnt[pairs[e] >> 17], 1);
    __syncthreads();
    if (t < 128) off[t] = cnt[t];
    __syncthreads();
    for (int o = 1; o < 128; o <<= 1) {           // Hillis-Steele inclusive scan
        int u = (t < 128 && t >= o) ? off[t - o] : 0;
        __syncthreads();
        if (t < 128) off[t] += u;
        __syncthreads();
    }
    if (t < 128) {
        int ex = e0 + off[t] - cnt[t];            // exclusive + bucket base
        cur[t] = ex;
        int node = (b << 7) + t;
        if (node < NN) {
            rowstart[node] = ex;
            dinv[node] = rsqrtf((float)cnt[t] + 1.0f);
        }
    }
    if (b == NB - 1 && t == 0) rowstart[NN] = e1; // == NE
    __syncthreads();
    for (int e = e0 + t; e < e1; e += 256) {
        unsigned pk = pairs[e];
        int pos = atomicAdd(&cur[pk >> 17], 1);
        srcidx[pos] = (int)(pk & 0x1FFFF);        // block-local contiguous region
    }
}

// ---------------- per-layer GEMM: y = bf16((h @ W^T) * dinv) ----------------
// LDS-staged h tile: coalesced independent global loads, broadcast ds_reads.
__global__ __launch_bounds__(256) void gemm_scale(const float* __restrict__ h,
                                                  const float* __restrict__ W,
                                                  const float* __restrict__ dinv,
                                                  unsigned short* __restrict__ y,
                                                  int nrows)
{
    __shared__ float hs[64 * 64];   // 16 KB tile
    const int t = threadIdx.x;
    const int lane = t & 63;
    const int wave = t >> 6;
    const int rbase = blockIdx.x * 64;
    const int valid = (nrows - rbase < 64) ? (nrows - rbase) : 64;

    // W[lane][:] into registers (L2-resident, amortized over 16 rows)
    float Wreg[64];
    const float4* Wv = (const float4*)(W + lane * 64);
#pragma unroll
    for (int k4 = 0; k4 < 16; ++k4) {
        float4 wv = Wv[k4];
        Wreg[k4 * 4 + 0] = wv.x; Wreg[k4 * 4 + 1] = wv.y;
        Wreg[k4 * 4 + 2] = wv.z; Wreg[k4 * 4 + 3] = wv.w;
    }

    // stage 64 rows coalesced: 1024 float4, 4 per thread, all independent
    const float4* hg = (const float4*)(h + (size_t)rbase * 64);
    float4* hsv = (float4*)hs;
#pragma unroll
    for (int j = 0; j < 4; ++j) {
        int f = t + j * 256;
        if ((f >> 4) < valid) hsv[f] = hg[f];
    }
    __syncthreads();

#pragma unroll 1
    for (int i = 0; i < 16; ++i) {
        int r = i * 4 + wave;               // interleaved: balanced in partial blocks
        if (r >= valid) break;
        const float4* hrow = (const float4*)(hs + r * 64);
        float a0 = 0.f, a1 = 0.f, a2 = 0.f, a3 = 0.f;
#pragma unroll
        for (int k4 = 0; k4 < 16; ++k4) {
            float4 hv = hrow[k4];           // LDS broadcast read (conflict-free)
            a0 = fmaf(hv.x, Wreg[k4 * 4 + 0], a0);
            a1 = fmaf(hv.y, Wreg[k4 * 4 + 1], a1);
            a2 = fmaf(hv.z, Wreg[k4 * 4 + 2], a2);
            a3 = fmaf(hv.w, Wreg[k4 * 4 + 3], a3);
        }
        int rg = rbase + r;
        y[(size_t)rg * 64 + lane] = f32_to_bf16(((a0 + a1) + (a2 + a3)) * dinv[rg]);
    }
}

// ---------------- pull aggregation: h[n] = relu((y[n] + sum_in y[src]) * dinv[n] + b) ----------------
__global__ __launch_bounds__(256) void pull_aggr(const int* __restrict__ rowstart,
                                                 const int* __restrict__ srcidx,
                                                 const unsigned short* __restrict__ y,
                                                 const float* __restrict__ dinv,
                                                 const float* __restrict__ bias,
                                                 float* __restrict__ hout)
{
    int wid = (blockIdx.x * blockDim.x + threadIdx.x) >> 6;
    int lane = threadIdx.x & 63;
    if (wid >= NN) return;
    int s0 = rowstart[wid], s1 = rowstart[wid + 1];
    float acc = bf16_to_f32(y[(size_t)wid * 64 + lane]);   // self-loop term (y = xw*dinv)
    for (int base = s0; base < s1; base += 64) {
        int nb = s1 - base; if (nb > 64) nb = 64;
        int idx = (lane < nb) ? srcidx[base + lane] : 0;   // coalesced batch of indices
        int j = 0;
        for (; j + 8 <= nb; j += 8) {                 // 8 independent gathers in flight
            int i0 = __shfl(idx, j + 0), i1 = __shfl(idx, j + 1);
            int i2 = __shfl(idx, j + 2), i3 = __shfl(idx, j + 3);
            int i4 = __shfl(idx, j + 4), i5 = __shfl(idx, j + 5);
            int i6 = __shfl(idx, j + 6), i7 = __shfl(idx, j + 7);
            unsigned short v0 = y[(size_t)i0 * 64 + lane];
            unsigned short v1 = y[(size_t)i1 * 64 + lane];
            unsigned short v2 = y[(size_t)i2 * 64 + lane];
            unsigned short v3 = y[(size_t)i3 * 64 + lane];
            unsigned short v4 = y[(size_t)i4 * 64 + lane];
            unsigned short v5 = y[(size_t)i5 * 64 + lane];
            unsigned short v6 = y[(size_t)i6 * 64 + lane];
            unsigned short v7 = y[(size_t)i7 * 64 + lane];
            acc += bf16_to_f32(v0); acc += bf16_to_f32(v1);
            acc += bf16_to_f32(v2); acc += bf16_to_f32(v3);
            acc += bf16_to_f32(v4); acc += bf16_to_f32(v5);
            acc += bf16_to_f32(v6); acc += bf16_to_f32(v7);
        }
        for (; j < nb; ++j) {
            int s = __shfl(idx, j);
            acc += bf16_to_f32(y[(size_t)s * 64 + lane]);
        }
    }
    float v = fmaf(acc, dinv[wid], bias[lane]);
    hout[(size_t)wid * 64 + lane] = fmaxf(v, 0.f);
}

// ---------------- pool (mean per graph, batch sorted) + FFN + softmax ----------------
__global__ __launch_bounds__(64) void pool_ffn(const float* __restrict__ h3,
                                               const int* __restrict__ batch,
                                               const float* __restrict__ Wf,
                                               const float* __restrict__ bf,
                                               float* __restrict__ pooled,
                                               float* __restrict__ ffn,
                                               float* __restrict__ soft)
{
    int g = blockIdx.x;
    int lane = threadIdx.x;

    int lo = 0, hi = NN;
    while (lo < hi) { int mid = (lo + hi) >> 1; if (batch[mid] < g) lo = mid + 1; else hi = mid; }
    int start = lo;
    lo = start; hi = NN;
    while (lo < hi) { int mid = (lo + hi) >> 1; if (batch[mid] < g + 1) lo = mid + 1; else hi = mid; }
    int end = lo;

    float acc = 0.f;
    for (int n = start; n < end; ++n) acc += h3[(size_t)n * 64 + lane];
    float cnt = (float)(end - start);
    float pv = acc / fmaxf(cnt, 1.0f);
    pooled[g * 64 + lane] = pv;

    float f = 0.f;
#pragma unroll
    for (int cls = 0; cls < NC; ++cls) {
        float v = pv * Wf[cls * 64 + lane];
#pragma unroll
        for (int off = 32; off; off >>= 1) v += __shfl_xor(v, off);
        if (lane == cls) f = v;
    }
    float fb = (lane < NC) ? fmaxf(f + bf[lane], 0.f) : -INFINITY;
    if (lane < NC) ffn[g * NC + lane] = fb;

    float m = fb;
#pragma unroll
    for (int off = 32; off; off >>= 1) m = fmaxf(m, __shfl_xor(m, off));
    float e = (lane < NC) ? expf(fb - m) : 0.f;
    float s = e;
#pragma unroll
    for (int off = 32; off; off >>= 1) s += __shfl_xor(s, off);
    if (lane < NC) soft[g * NC + lane] = e / s;
}

extern "C" void kernel_launch(void* const* d_in, const int* in_sizes, int n_in,
                              void* d_out, int out_size, void* d_ws, size_t ws_size,
                              hipStream_t stream) {
    const float* x   = (const float*)d_in[0];
    const int*   ei  = (const int*)d_in[1];
    const int*   bat = (const int*)d_in[2];
    const float* W1  = (const float*)d_in[3];
    const float* b1  = (const float*)d_in[4];
    const float* W2  = (const float*)d_in[5];
    const float* b2  = (const float*)d_in[6];
    const float* W3  = (const float*)d_in[7];
    const float* b3  = (const float*)d_in[8];
    const float* Wf  = (const float*)d_in[9];
    const float* bf  = (const float*)d_in[10];

    const int* src = ei;
    const int* dst = ei + NE;

    float* out    = (float*)d_out;
    float* h1     = out;
    float* h2     = out + (size_t)NN * HD;
    float* h3     = out + (size_t)2 * NN * HD;
    float* pooled = out + (size_t)3 * NN * HD;
    float* ffn    = pooled + (size_t)NG * HD;
    float* soft   = ffn + (size_t)NG * NC;

    // workspace layout (bytes):
    //   dinv      [NN f32]        @ 0
    //   rowstart  [NN+1 i32]      @ 400000
    //   srcidx    [NE i32]        @ 800016          (ends 7,200,016)
    //   y         [NN*64 bf16]    @ 7200016         (ends 20,000,016)
    //   -- partition temporaries overlap y (dead before first gemm writes y):
    //   pairs     [NE u32]        @ 7200016         (ends 13,600,016)
    //   hist      [NB*NBLK i32]   @ 13600016        (613,088 B)
    //   btotal    [NB i32]        @ 14213104
    //   bucketoff [NB+1 i32]      @ 14216232
    char* ws = (char*)d_ws;
    float*          dinv      = (float*)(ws + 0);
    int*            rowstart  = (int*)(ws + 400000);
    int*            srcidx    = (int*)(ws + 800016);
    unsigned short* y         = (unsigned short*)(ws + 7200016);
    unsigned*       pairs     = (unsigned*)(ws + 7200016);
    int*            hist      = (int*)(ws + 13600016);
    int*            btotal    = (int*)(ws + 14213104);
    int*            bucketoff = (int*)(ws + 14216232);

    // ---- edge partition + per-bucket counting sort (amortized across 3 layers) ----
    hist_buckets<<<NBLK, 256, 0, stream>>>(dst, hist);
    bucket_total<<<(NB + 3) / 4, 256, 0, stream>>>(hist, btotal);
    scan_totals<<<1, 1024, 0, stream>>>(btotal, bucketoff);
    scan_hist<<<(NB + 3) / 4, 256, 0, stream>>>(hist, bucketoff);
    bin_edges<<<NBLK, 256, 0, stream>>>(src, dst, hist, pairs);
    sort_bucket<<<NB, 256, 0, stream>>>(bucketoff, pairs, rowstart, srcidx, dinv);

    const int gemmGrid = (NN + 63) / 64;
    const int aggrGrid = (NN + 3) / 4;      // 4 waves (nodes) per 256-block

    gemm_scale<<<gemmGrid, 256, 0, stream>>>(x, W1, dinv, y, NN);
    pull_aggr<<<aggrGrid, 256, 0, stream>>>(rowstart, srcidx, y, dinv, b1, h1);

    gemm_scale<<<gemmGrid, 256, 0, stream>>>(h1, W2, dinv, y, NN);
    pull_aggr<<<aggrGrid, 256, 0, stream>>>(rowstart, srcidx, y, dinv, b2, h2);

    gemm_scale<<<gemmGrid, 256, 0, stream>>>(h2, W3, dinv, y, NN);
    pull_aggr<<<aggrGrid, 256, 0, stream>>>(rowstart, srcidx, y, dinv, b3, h3);

    pool_ffn<<<NG, 64, 0, stream>>>(h3, bat, Wf, bf, pooled, ffn, soft);
}

// Round 8
// 376.228 us; speedup vs baseline: 6.3970x; 1.0899x over previous
//
#include <hip/hip_runtime.h>
#include <hip/hip_bf16.h>
#include <math.h>

#define NN 100000      // nodes
#define NE 1600000     // edges
#define HD 64          // feature dim
#define NG 1000        // graphs
#define NC 10          // classes

#define NB 782         // buckets = ceil(NN/128), bucket = dst>>7 (128-node range)
#define NBLK 196       // partition blocks (keep ~10-edge runs per bucket -> low write-amp)
#define EPB 8164       // edges per partition block = ceil(NE/NBLK)

__device__ __forceinline__ unsigned short f32_to_bf16(float f) {
    union { float f; unsigned u; } c; c.f = f;
    unsigned u = c.u;
    u += 0x7FFFu + ((u >> 16) & 1u);   // round-to-nearest-even
    return (unsigned short)(u >> 16);
}
#define BFLO(u) __uint_as_float((u) << 16)
#define BFHI(u) __uint_as_float((u) & 0xFFFF0000u)

// ---------------- pass 1a: per-block bucket histogram ----------------
__global__ __launch_bounds__(256) void hist_buckets(const int* __restrict__ dst,
                                                    int* __restrict__ hist)
{
    __shared__ int cnt[NB];
    int t = threadIdx.x, blk = blockIdx.x;
    for (int i = t; i < NB; i += 256) cnt[i] = 0;
    __syncthreads();
    int e0 = blk * EPB;
    int e1 = e0 + EPB; if (e1 > NE) e1 = NE;
    for (int e = e0 + t; e < e1; e += 256) atomicAdd(&cnt[dst[e] >> 7], 1);
    __syncthreads();
    for (int i = t; i < NB; i += 256) hist[(size_t)i * NBLK + blk] = cnt[i];
}

// ---------------- pass 1b: per-bucket totals ----------------
__global__ __launch_bounds__(256) void bucket_total(const int* __restrict__ hist,
                                                    int* __restrict__ btotal)
{
    int w = (blockIdx.x * 256 + threadIdx.x) >> 6;
    int lane = threadIdx.x & 63;
    if (w >= NB) return;
    const int* row = hist + (size_t)w * NBLK;
    int s = 0;
    for (int i = lane; i < NBLK; i += 64) s += row[i];
#pragma unroll
    for (int off = 32; off; off >>= 1) s += __shfl_xor(s, off);
    if (lane == 0) btotal[w] = s;
}

// ---------------- pass 1c: scan bucket totals -> bucketoff ----------------
__global__ __launch_bounds__(1024) void scan_totals(const int* __restrict__ btotal,
                                                    int* __restrict__ bucketoff)
{
    __shared__ int sm[1024];
    int t = threadIdx.x;
    int v = (t < NB) ? btotal[t] : 0;
    sm[t] = v;
    __syncthreads();
    for (int off = 1; off < 1024; off <<= 1) {
        int u = (t >= off) ? sm[t - off] : 0;
        __syncthreads();
        sm[t] += u;
        __syncthreads();
    }
    if (t <= NB) bucketoff[t] = sm[t] - ((t < NB) ? v : 0);
}

// ---------------- pass 1d: hist counts -> global write offsets (in place) ----------------
__global__ __launch_bounds__(256) void scan_hist(int* __restrict__ hist,
                                                 const int* __restrict__ bucketoff)
{
    int w = (blockIdx.x * 256 + threadIdx.x) >> 6;
    int lane = threadIdx.x & 63;
    if (w >= NB) return;
    int run = bucketoff[w];
    int* row = hist + (size_t)w * NBLK;
    for (int c0 = 0; c0 < NBLK; c0 += 64) {
        int idx = c0 + lane;
        int v = (idx < NBLK) ? row[idx] : 0;
        int incl = v;
#pragma unroll
        for (int off = 1; off < 64; off <<= 1) {
            int u = __shfl_up(incl, off);
            if (lane >= off) incl += u;
        }
        if (idx < NBLK) row[idx] = run + incl - v;
        run += __shfl(incl, 63);
    }
}

// ---------------- pass 2: bin edges -> packed pairs (row7|src17), grouped by bucket ----------------
__global__ __launch_bounds__(256) void bin_edges(const int* __restrict__ src,
                                                 const int* __restrict__ dst,
                                                 const int* __restrict__ hist,
                                                 unsigned* __restrict__ pairs)
{
    __shared__ int cur[NB];
    int t = threadIdx.x, blk = blockIdx.x;
    for (int i = t; i < NB; i += 256) cur[i] = hist[(size_t)i * NBLK + blk];
    __syncthreads();
    int e0 = blk * EPB;
    int e1 = e0 + EPB; if (e1 > NE) e1 = NE;
    for (int e = e0 + t; e < e1; e += 256) {
        int d = dst[e], s = src[e];
        int b = d >> 7;
        int pos = atomicAdd(&cur[b], 1);
        pairs[pos] = ((unsigned)(d & 127) << 17) | (unsigned)s;
    }
}

// ---------------- pass 3: per-bucket counting sort -> srcidx (dst-sorted), rowstart, dinv ----------------
__global__ __launch_bounds__(256) void sort_bucket(const int* __restrict__ bucketoff,
                                                   const unsigned* __restrict__ pairs,
                                                   int* __restrict__ rowstart,
                                                   int* __restrict__ srcidx,
                                                   float* __restrict__ dinv)
{
    __shared__ int cnt[128], off[128], cur[128];
    int b = blockIdx.x, t = threadIdx.x;
    int e0 = bucketoff[b], e1 = bucketoff[b + 1];
    if (t < 128) cnt[t] = 0;
    __syncthreads();
    for (int e = e0 + t; e < e1; e += 256) atomicAdd(&cnt[pairs[e] >> 17], 1);
    __syncthreads();
    if (t < 128) off[t] = cnt[t];
    __syncthreads();
    for (int o = 1; o < 128; o <<= 1) {           // Hillis-Steele inclusive scan
        int u = (t < 128 && t >= o) ? off[t - o] : 0;
        __syncthreads();
        if (t < 128) off[t] += u;
        __syncthreads();
    }
    if (t < 128) {
        int ex = e0 + off[t] - cnt[t];            // exclusive + bucket base
        cur[t] = ex;
        int node = (b << 7) + t;
        if (node < NN) {
            rowstart[node] = ex;
            dinv[node] = rsqrtf((float)cnt[t] + 1.0f);
        }
    }
    if (b == NB - 1 && t == 0) rowstart[NN] = e1; // == NE
    __syncthreads();
    for (int e = e0 + t; e < e1; e += 256) {
        unsigned pk = pairs[e];
        int pos = atomicAdd(&cur[pk >> 17], 1);
        srcidx[pos] = (int)(pk & 0x1FFFF);        // block-local contiguous region
    }
}

// ---------------- graph boundaries on sorted batch ----------------
__global__ __launch_bounds__(256) void graph_bounds(const int* __restrict__ batch,
                                                    int* __restrict__ gstart)
{
    int i = blockIdx.x * 256 + threadIdx.x;
    if (i >= NN) return;
    int b = batch[i];
    if (i == 0) {
        for (int g = 0; g <= b; ++g) gstart[g] = 0;
    } else {
        int p = batch[i - 1];
        for (int g = p + 1; g <= b; ++g) gstart[g] = i;
    }
    if (i == NN - 1) {
        for (int g = b + 1; g <= NG; ++g) gstart[g] = NN;
    }
}

// ---------------- per-layer GEMM: y = bf16((h @ W^T) * dinv) ----------------
__global__ __launch_bounds__(256) void gemm_scale(const float* __restrict__ h,
                                                  const float* __restrict__ W,
                                                  const float* __restrict__ dinv,
                                                  unsigned short* __restrict__ y,
                                                  int nrows)
{
    __shared__ float hs[64 * 64];   // 16 KB tile
    const int t = threadIdx.x;
    const int lane = t & 63;
    const int wave = t >> 6;
    const int rbase = blockIdx.x * 64;
    const int valid = (nrows - rbase < 64) ? (nrows - rbase) : 64;

    float Wreg[64];
    const float4* Wv = (const float4*)(W + lane * 64);
#pragma unroll
    for (int k4 = 0; k4 < 16; ++k4) {
        float4 wv = Wv[k4];
        Wreg[k4 * 4 + 0] = wv.x; Wreg[k4 * 4 + 1] = wv.y;
        Wreg[k4 * 4 + 2] = wv.z; Wreg[k4 * 4 + 3] = wv.w;
    }

    const float4* hg = (const float4*)(h + (size_t)rbase * 64);
    float4* hsv = (float4*)hs;
#pragma unroll
    for (int j = 0; j < 4; ++j) {
        int f = t + j * 256;
        if ((f >> 4) < valid) hsv[f] = hg[f];
    }
    __syncthreads();

#pragma unroll 1
    for (int i = 0; i < 16; ++i) {
        int r = i * 4 + wave;
        if (r >= valid) break;
        const float4* hrow = (const float4*)(hs + r * 64);
        float a0 = 0.f, a1 = 0.f, a2 = 0.f, a3 = 0.f;
#pragma unroll
        for (int k4 = 0; k4 < 16; ++k4) {
            float4 hv = hrow[k4];
            a0 = fmaf(hv.x, Wreg[k4 * 4 + 0], a0);
            a1 = fmaf(hv.y, Wreg[k4 * 4 + 1], a1);
            a2 = fmaf(hv.z, Wreg[k4 * 4 + 2], a2);
            a3 = fmaf(hv.w, Wreg[k4 * 4 + 3], a3);
        }
        int rg = rbase + r;
        y[(size_t)rg * 64 + lane] = f32_to_bf16(((a0 + a1) + (a2 + a3)) * dinv[rg]);
    }
}

// ---------------- pull aggregation (dword gathers: 2 edges per wave-load) ----------------
// lane fl=lane&31 holds features {2fl, 2fl+1}; half 0/1 process alternate edges.
__global__ __launch_bounds__(256) void pull_aggr(const int* __restrict__ rowstart,
                                                 const int* __restrict__ srcidx,
                                                 const unsigned* __restrict__ y,   // 32 u32 per row
                                                 const float* __restrict__ dinv,
                                                 const float* __restrict__ bias,
                                                 float* __restrict__ hout)
{
    int wid = (blockIdx.x * blockDim.x + threadIdx.x) >> 6;
    int lane = threadIdx.x & 63;
    if (wid >= NN) return;
    const int fl = lane & 31;
    const int half = lane >> 5;

    unsigned su = y[(size_t)wid * 32 + fl];        // self-loop term (both halves load; half1 zeroed)
    float acc0 = half ? 0.f : BFLO(su);
    float acc1 = half ? 0.f : BFHI(su);

    int s0 = rowstart[wid], s1 = rowstart[wid + 1];
    for (int base = s0; base < s1; base += 64) {
        int nb = s1 - base; if (nb > 64) nb = 64;
        int idx = (lane < nb) ? srcidx[base + lane] : 0;   // coalesced batch of indices
        int j = 0;
        for (; j + 16 <= nb; j += 16) {            // 8 dword loads = 16 edges in flight
            int a0 = __shfl(idx, j + 0),  b0 = __shfl(idx, j + 1);
            int a1 = __shfl(idx, j + 2),  b1 = __shfl(idx, j + 3);
            int a2 = __shfl(idx, j + 4),  b2 = __shfl(idx, j + 5);
            int a3 = __shfl(idx, j + 6),  b3 = __shfl(idx, j + 7);
            int a4 = __shfl(idx, j + 8),  b4 = __shfl(idx, j + 9);
            int a5 = __shfl(idx, j + 10), b5 = __shfl(idx, j + 11);
            int a6 = __shfl(idx, j + 12), b6 = __shfl(idx, j + 13);
            int a7 = __shfl(idx, j + 14), b7 = __shfl(idx, j + 15);
            int e0 = half ? b0 : a0, e1 = half ? b1 : a1;
            int e2 = half ? b2 : a2, e3 = half ? b3 : a3;
            int e4 = half ? b4 : a4, e5 = half ? b5 : a5;
            int e6 = half ? b6 : a6, e7 = half ? b7 : a7;
            unsigned u0 = y[(size_t)e0 * 32 + fl];
            unsigned u1 = y[(size_t)e1 * 32 + fl];
            unsigned u2 = y[(size_t)e2 * 32 + fl];
            unsigned u3 = y[(size_t)e3 * 32 + fl];
            unsigned u4 = y[(size_t)e4 * 32 + fl];
            unsigned u5 = y[(size_t)e5 * 32 + fl];
            unsigned u6 = y[(size_t)e6 * 32 + fl];
            unsigned u7 = y[(size_t)e7 * 32 + fl];
            acc0 += BFLO(u0); acc1 += BFHI(u0);
            acc0 += BFLO(u1); acc1 += BFHI(u1);
            acc0 += BFLO(u2); acc1 += BFHI(u2);
            acc0 += BFLO(u3); acc1 += BFHI(u3);
            acc0 += BFLO(u4); acc1 += BFHI(u4);
            acc0 += BFLO(u5); acc1 += BFHI(u5);
            acc0 += BFLO(u6); acc1 += BFHI(u6);
            acc0 += BFLO(u7); acc1 += BFHI(u7);
        }
        for (; j + 2 <= nb; j += 2) {              // pair tail
            int a = __shfl(idx, j), b = __shfl(idx, j + 1);
            int e = half ? b : a;
            unsigned u = y[(size_t)e * 32 + fl];
            acc0 += BFLO(u); acc1 += BFHI(u);
        }
        if (j < nb) {                              // odd edge: half0 only
            int a = __shfl(idx, j);
            unsigned u = y[(size_t)a * 32 + fl];
            if (!half) { acc0 += BFLO(u); acc1 += BFHI(u); }
        }
    }

    acc0 += __shfl_xor(acc0, 32);                  // merge halves
    acc1 += __shfl_xor(acc1, 32);
    if (half == 0) {
        float d = dinv[wid];
        float2 bb = ((const float2*)bias)[fl];
        float2 v;
        v.x = fmaxf(fmaf(acc0, d, bb.x), 0.f);
        v.y = fmaxf(fmaf(acc1, d, bb.y), 0.f);
        ((float2*)hout)[(size_t)wid * 32 + fl] = v;
    }
}

// ---------------- pool (mean per graph, precomputed bounds) + FFN + softmax ----------------
__global__ __launch_bounds__(256) void pool_ffn(const float* __restrict__ h3,
                                                const int* __restrict__ gstart,
                                                const float* __restrict__ Wf,
                                                const float* __restrict__ bf,
                                                float* __restrict__ pooled,
                                                float* __restrict__ ffn,
                                                float* __restrict__ soft)
{
    __shared__ float part[4][64];
    int g = blockIdx.x;
    int t = threadIdx.x, wv = t >> 6, lane = t & 63;
    int start = gstart[g], end = gstart[g + 1];

    float acc = 0.f;
    for (int n = start + wv; n < end; n += 4) acc += h3[(size_t)n * 64 + lane];
    part[wv][lane] = acc;
    __syncthreads();
    if (wv != 0) return;

    float a = part[0][lane] + part[1][lane] + part[2][lane] + part[3][lane];
    float cnt = (float)(end - start);
    float pv = a / fmaxf(cnt, 1.0f);
    pooled[g * 64 + lane] = pv;

    float f = 0.f;
#pragma unroll
    for (int cls = 0; cls < NC; ++cls) {
        float v = pv * Wf[cls * 64 + lane];
#pragma unroll
        for (int off = 32; off; off >>= 1) v += __shfl_xor(v, off);
        if (lane == cls) f = v;
    }
    float fb = (lane < NC) ? fmaxf(f + bf[lane], 0.f) : -INFINITY;
    if (lane < NC) ffn[g * NC + lane] = fb;

    float m = fb;
#pragma unroll
    for (int off = 32; off; off >>= 1) m = fmaxf(m, __shfl_xor(m, off));
    float e = (lane < NC) ? expf(fb - m) : 0.f;
    float s = e;
#pragma unroll
    for (int off = 32; off; off >>= 1) s += __shfl_xor(s, off);
    if (lane < NC) soft[g * NC + lane] = e / s;
}

extern "C" void kernel_launch(void* const* d_in, const int* in_sizes, int n_in,
                              void* d_out, int out_size, void* d_ws, size_t ws_size,
                              hipStream_t stream) {
    const float* x   = (const float*)d_in[0];
    const int*   ei  = (const int*)d_in[1];
    const int*   bat = (const int*)d_in[2];
    const float* W1  = (const float*)d_in[3];
    const float* b1  = (const float*)d_in[4];
    const float* W2  = (const float*)d_in[5];
    const float* b2  = (const float*)d_in[6];
    const float* W3  = (const float*)d_in[7];
    const float* b3  = (const float*)d_in[8];
    const float* Wf  = (const float*)d_in[9];
    const float* bf  = (const float*)d_in[10];

    const int* src = ei;
    const int* dst = ei + NE;

    float* out    = (float*)d_out;
    float* h1     = out;
    float* h2     = out + (size_t)NN * HD;
    float* h3     = out + (size_t)2 * NN * HD;
    float* pooled = out + (size_t)3 * NN * HD;
    float* ffn    = pooled + (size_t)NG * HD;
    float* soft   = ffn + (size_t)NG * NC;

    // workspace layout (bytes):
    //   dinv      [NN f32]        @ 0
    //   rowstart  [NN+1 i32]      @ 400000
    //   srcidx    [NE i32]        @ 800016          (ends 7,200,016)
    //   y         [NN*64 bf16]    @ 7200016         (ends 20,000,016)
    //   gstart    [NG+1 i32]      @ 20000016        (outside y -- y is written later!)
    //   -- partition temporaries overlap y (dead before first gemm writes y):
    //   pairs     [NE u32]        @ 7200016         (ends 13,600,016)
    //   hist      [NB*NBLK i32]   @ 13600016        (613,088 B)
    //   btotal    [NB i32]        @ 14213104
    //   bucketoff [NB+1 i32]      @ 14216232
    char* ws = (char*)d_ws;
    float*          dinv      = (float*)(ws + 0);
    int*            rowstart  = (int*)(ws + 400000);
    int*            srcidx    = (int*)(ws + 800016);
    unsigned short* y         = (unsigned short*)(ws + 7200016);
    int*            gstart    = (int*)(ws + 20000016);
    unsigned*       pairs     = (unsigned*)(ws + 7200016);
    int*            hist      = (int*)(ws + 13600016);
    int*            btotal    = (int*)(ws + 14213104);
    int*            bucketoff = (int*)(ws + 14216232);

    // ---- edge partition + per-bucket counting sort (amortized across 3 layers) ----
    hist_buckets<<<NBLK, 256, 0, stream>>>(dst, hist);
    bucket_total<<<(NB + 3) / 4, 256, 0, stream>>>(hist, btotal);
    scan_totals<<<1, 1024, 0, stream>>>(btotal, bucketoff);
    scan_hist<<<(NB + 3) / 4, 256, 0, stream>>>(hist, bucketoff);
    bin_edges<<<NBLK, 256, 0, stream>>>(src, dst, hist, pairs);
    sort_bucket<<<NB, 256, 0, stream>>>(bucketoff, pairs, rowstart, srcidx, dinv);
    graph_bounds<<<(NN + 255) / 256, 256, 0, stream>>>(bat, gstart);

    const int gemmGrid = (NN + 63) / 64;
    const int aggrGrid = (NN + 3) / 4;      // 4 waves (nodes) per 256-block

    gemm_scale<<<gemmGrid, 256, 0, stream>>>(x, W1, dinv, y, NN);
    pull_aggr<<<aggrGrid, 256, 0, stream>>>(rowstart, srcidx, (const unsigned*)y, dinv, b1, h1);

    gemm_scale<<<gemmGrid, 256, 0, stream>>>(h1, W2, dinv, y, NN);
    pull_aggr<<<aggrGrid, 256, 0, stream>>>(rowstart, srcidx, (const unsigned*)y, dinv, b2, h2);

    gemm_scale<<<gemmGrid, 256, 0, stream>>>(h2, W3, dinv, y, NN);
    pull_aggr<<<aggrGrid, 256, 0, stream>>>(rowstart, srcidx, (const unsigned*)y, dinv, b3, h3);

    pool_ffn<<<NG, 256, 0, stream>>>(h3, gstart, Wf, bf, pooled, ffn, soft);
}

// Round 9
// 296.047 us; speedup vs baseline: 8.1296x; 1.2708x over previous
//
#include <hip/hip_runtime.h>
#include <hip/hip_bf16.h>
#include <math.h>

#define NN 100000      // nodes
#define NE 1600000     // edges
#define HD 64          // feature dim
#define NG 1000        // graphs
#define NC 10          // classes

#define NB 782         // buckets = ceil(NN/128), bucket = dst>>7 (128-node range)
#define NBLK 196       // partition blocks
#define EPB 8164       // edges per partition block = ceil(NE/NBLK)

typedef __attribute__((ext_vector_type(8))) short bf16x8;
typedef __attribute__((ext_vector_type(4))) float f32x4;

__device__ __forceinline__ unsigned short f32_to_bf16(float f) {
    union { float f; unsigned u; } c; c.f = f;
    unsigned u = c.u;
    u += 0x7FFFu + ((u >> 16) & 1u);   // round-to-nearest-even
    return (unsigned short)(u >> 16);
}
#define BFLO(u) __uint_as_float((u) << 16)
#define BFHI(u) __uint_as_float((u) & 0xFFFF0000u)

// ---------------- pass 1a: per-block bucket histogram ----------------
__global__ __launch_bounds__(256) void hist_buckets(const int* __restrict__ dst,
                                                    int* __restrict__ hist)
{
    __shared__ int cnt[NB];
    int t = threadIdx.x, blk = blockIdx.x;
    for (int i = t; i < NB; i += 256) cnt[i] = 0;
    __syncthreads();
    int e0 = blk * EPB;
    int e1 = e0 + EPB; if (e1 > NE) e1 = NE;
    for (int e = e0 + t; e < e1; e += 256) atomicAdd(&cnt[dst[e] >> 7], 1);
    __syncthreads();
    for (int i = t; i < NB; i += 256) hist[(size_t)i * NBLK + blk] = cnt[i];
}

// ---------------- pass 1b: per-bucket totals ----------------
__global__ __launch_bounds__(256) void bucket_total(const int* __restrict__ hist,
                                                    int* __restrict__ btotal)
{
    int w = (blockIdx.x * 256 + threadIdx.x) >> 6;
    int lane = threadIdx.x & 63;
    if (w >= NB) return;
    const int* row = hist + (size_t)w * NBLK;
    int s = 0;
    for (int i = lane; i < NBLK; i += 64) s += row[i];
#pragma unroll
    for (int off = 32; off; off >>= 1) s += __shfl_xor(s, off);
    if (lane == 0) btotal[w] = s;
}

// ---------------- pass 1c: scan bucket totals -> bucketoff ----------------
__global__ __launch_bounds__(1024) void scan_totals(const int* __restrict__ btotal,
                                                    int* __restrict__ bucketoff)
{
    __shared__ int sm[1024];
    int t = threadIdx.x;
    int v = (t < NB) ? btotal[t] : 0;
    sm[t] = v;
    __syncthreads();
    for (int off = 1; off < 1024; off <<= 1) {
        int u = (t >= off) ? sm[t - off] : 0;
        __syncthreads();
        sm[t] += u;
        __syncthreads();
    }
    if (t <= NB) bucketoff[t] = sm[t] - ((t < NB) ? v : 0);
}

// ---------------- pass 1d: hist counts -> global write offsets (in place) ----------------
__global__ __launch_bounds__(256) void scan_hist(int* __restrict__ hist,
                                                 const int* __restrict__ bucketoff)
{
    int w = (blockIdx.x * 256 + threadIdx.x) >> 6;
    int lane = threadIdx.x & 63;
    if (w >= NB) return;
    int run = bucketoff[w];
    int* row = hist + (size_t)w * NBLK;
    for (int c0 = 0; c0 < NBLK; c0 += 64) {
        int idx = c0 + lane;
        int v = (idx < NBLK) ? row[idx] : 0;
        int incl = v;
#pragma unroll
        for (int off = 1; off < 64; off <<= 1) {
            int u = __shfl_up(incl, off);
            if (lane >= off) incl += u;
        }
        if (idx < NBLK) row[idx] = run + incl - v;
        run += __shfl(incl, 63);
    }
}

// ---------------- pass 2: bin edges -> packed pairs (row7|src17), grouped by bucket ----------------
__global__ __launch_bounds__(256) void bin_edges(const int* __restrict__ src,
                                                 const int* __restrict__ dst,
                                                 const int* __restrict__ hist,
                                                 unsigned* __restrict__ pairs)
{
    __shared__ int cur[NB];
    int t = threadIdx.x, blk = blockIdx.x;
    for (int i = t; i < NB; i += 256) cur[i] = hist[(size_t)i * NBLK + blk];
    __syncthreads();
    int e0 = blk * EPB;
    int e1 = e0 + EPB; if (e1 > NE) e1 = NE;
    for (int e = e0 + t; e < e1; e += 256) {
        int d = dst[e], s = src[e];
        int b = d >> 7;
        int pos = atomicAdd(&cur[b], 1);
        pairs[pos] = ((unsigned)(d & 127) << 17) | (unsigned)s;
    }
}

// ---------------- pass 3: per-bucket counting sort by (row, src-slab) ----------------
// key = row*8 | (src>>14): srcidx comes out dst-sorted AND slab-grouped within each
// row -> co-resident waves gather from a ~2MB y-slab at a time (L2-resident).
__global__ __launch_bounds__(256) void sort_bucket(const int* __restrict__ bucketoff,
                                                   const unsigned* __restrict__ pairs,
                                                   int* __restrict__ rowstart,
                                                   int* __restrict__ srcidx,
                                                   float* __restrict__ dinv)
{
    __shared__ int cnt[1024], boff[1024], wsum[256];
    int b = blockIdx.x, t = threadIdx.x;
    int e0 = bucketoff[b], e1 = bucketoff[b + 1];
    for (int i = t; i < 1024; i += 256) cnt[i] = 0;
    __syncthreads();
    for (int e = e0 + t; e < e1; e += 256) {
        unsigned pk = pairs[e];
        int key = (int)((pk >> 17) << 3) | (int)((pk & 0x1FFFFu) >> 14);
        atomicAdd(&cnt[key], 1);
    }
    __syncthreads();
    // scan 1024 bins: thread t owns bins 4t..4t+3
    int base4 = t * 4;
    int s0 = cnt[base4], s1 = cnt[base4 + 1], s2 = cnt[base4 + 2], s3 = cnt[base4 + 3];
    wsum[t] = s0 + s1 + s2 + s3;
    __syncthreads();
    for (int o = 1; o < 256; o <<= 1) {
        int u = (t >= o) ? wsum[t - o] : 0;
        __syncthreads();
        wsum[t] += u;
        __syncthreads();
    }
    int run = e0 + ((t > 0) ? wsum[t - 1] : 0);
    boff[base4]     = run;
    boff[base4 + 1] = run + s0;
    boff[base4 + 2] = run + s0 + s1;
    boff[base4 + 3] = run + s0 + s1 + s2;
    __syncthreads();
    if (t < 128) {
        int rs = boff[t * 8];
        int re = (t < 127) ? boff[t * 8 + 8] : e1;
        int node = (b << 7) + t;
        if (node < NN) {
            rowstart[node] = rs;
            dinv[node] = rsqrtf((float)(re - rs) + 1.0f);
        }
    }
    if (b == NB - 1 && t == 0) rowstart[NN] = e1;
    __syncthreads();     // rowstart reads done before boff is mutated as cursor
    for (int e = e0 + t; e < e1; e += 256) {
        unsigned pk = pairs[e];
        int key = (int)((pk >> 17) << 3) | (int)((pk & 0x1FFFFu) >> 14);
        int pos = atomicAdd(&boff[key], 1);
        srcidx[pos] = (int)(pk & 0x1FFFF);
    }
}

// ---------------- graph boundaries on sorted batch ----------------
__global__ __launch_bounds__(256) void graph_bounds(const int* __restrict__ batch,
                                                    int* __restrict__ gstart)
{
    int i = blockIdx.x * 256 + threadIdx.x;
    if (i >= NN) return;
    int b = batch[i];
    if (i == 0) {
        for (int g = 0; g <= b; ++g) gstart[g] = 0;
    } else {
        int p = batch[i - 1];
        for (int g = p + 1; g <= b; ++g) gstart[g] = i;
    }
    if (i == NN - 1) {
        for (int g = b + 1; g <= NG; ++g) gstart[g] = NN;
    }
}

// ---------------- per-layer GEMM via MFMA: y = bf16((h @ W^T) * dinv) ----------------
// mfma_f32_16x16x32_bf16. A: lane l -> h[m0+(l&15)][ (l>>4)*8+j ]; B: lane l ->
// W[c*16+(l&15)][ kb*32+(l>>4)*8+j ]; D: col=l&15, row=(l>>4)*4+reg (m89-verified).
__global__ __launch_bounds__(256) void gemm_mfma(const float* __restrict__ h,
                                                 const float* __restrict__ W,
                                                 const float* __restrict__ dinv,
                                                 unsigned short* __restrict__ y,
                                                 int nrows)
{
    const int t = threadIdx.x;
    const int lane = t & 63;
    const int wave = t >> 6;
    const int rbase = blockIdx.x * 64;
    const int l15 = lane & 15;
    const int kq  = lane >> 4;               // 0..3

    // B fragments (W in bf16): [ctile][khalf]
    bf16x8 Bf[4][2];
#pragma unroll
    for (int c = 0; c < 4; ++c) {
#pragma unroll
        for (int kb = 0; kb < 2; ++kb) {
            const float* wp = W + (c * 16 + l15) * 64 + kb * 32 + kq * 8;
            float f[8];
            *(float4*)(f)     = *(const float4*)(wp);
            *(float4*)(f + 4) = *(const float4*)(wp + 4);
            bf16x8 v;
#pragma unroll
            for (int i = 0; i < 8; ++i) v[i] = (short)f32_to_bf16(f[i]);
            Bf[c][kb] = v;
        }
    }

    // A fragments (h rows in bf16), row clamped for the partial last block
    int arow = rbase + wave * 16 + l15;
    if (arow >= nrows) arow = nrows - 1;
    bf16x8 Af[2];
#pragma unroll
    for (int kb = 0; kb < 2; ++kb) {
        const float* hp = h + (size_t)arow * 64 + kb * 32 + kq * 8;
        float f[8];
        *(float4*)(f)     = *(const float4*)(hp);
        *(float4*)(f + 4) = *(const float4*)(hp + 4);
        bf16x8 v;
#pragma unroll
        for (int i = 0; i < 8; ++i) v[i] = (short)f32_to_bf16(f[i]);
        Af[kb] = v;
    }

    f32x4 acc[4] = {{0.f,0.f,0.f,0.f},{0.f,0.f,0.f,0.f},{0.f,0.f,0.f,0.f},{0.f,0.f,0.f,0.f}};
#pragma unroll
    for (int c = 0; c < 4; ++c) {
        acc[c] = __builtin_amdgcn_mfma_f32_16x16x32_bf16(Af[0], Bf[c][0], acc[c], 0, 0, 0);
        acc[c] = __builtin_amdgcn_mfma_f32_16x16x32_bf16(Af[1], Bf[c][1], acc[c], 0, 0, 0);
    }

    const int drow0 = rbase + wave * 16 + kq * 4;
#pragma unroll
    for (int r = 0; r < 4; ++r) {
        int rg = drow0 + r;
        if (rg < nrows) {
            float d = dinv[rg];
#pragma unroll
            for (int c = 0; c < 4; ++c)
                y[(size_t)rg * 64 + c * 16 + l15] = f32_to_bf16(acc[c][r] * d);
        }
    }
}

// ---------------- pull aggregation (dword gathers: 2 edges per wave-load) ----------------
__global__ __launch_bounds__(256) void pull_aggr(const int* __restrict__ rowstart,
                                                 const int* __restrict__ srcidx,
                                                 const unsigned* __restrict__ y,   // 32 u32 per row
                                                 const float* __restrict__ dinv,
                                                 const float* __restrict__ bias,
                                                 float* __restrict__ hout)
{
    int wid = (blockIdx.x * blockDim.x + threadIdx.x) >> 6;
    int lane = threadIdx.x & 63;
    if (wid >= NN) return;
    const int fl = lane & 31;
    const int half = lane >> 5;

    unsigned su = y[(size_t)wid * 32 + fl];
    float acc0 = half ? 0.f : BFLO(su);
    float acc1 = half ? 0.f : BFHI(su);

    int s0 = rowstart[wid], s1 = rowstart[wid + 1];
    for (int base = s0; base < s1; base += 64) {
        int nb = s1 - base; if (nb > 64) nb = 64;
        int idx = (lane < nb) ? srcidx[base + lane] : 0;
        int j = 0;
        for (; j + 16 <= nb; j += 16) {
            int a0 = __shfl(idx, j + 0),  b0 = __shfl(idx, j + 1);
            int a1 = __shfl(idx, j + 2),  b1 = __shfl(idx, j + 3);
            int a2 = __shfl(idx, j + 4),  b2 = __shfl(idx, j + 5);
            int a3 = __shfl(idx, j + 6),  b3 = __shfl(idx, j + 7);
            int a4 = __shfl(idx, j + 8),  b4 = __shfl(idx, j + 9);
            int a5 = __shfl(idx, j + 10), b5 = __shfl(idx, j + 11);
            int a6 = __shfl(idx, j + 12), b6 = __shfl(idx, j + 13);
            int a7 = __shfl(idx, j + 14), b7 = __shfl(idx, j + 15);
            int e0 = half ? b0 : a0, e1 = half ? b1 : a1;
            int e2 = half ? b2 : a2, e3 = half ? b3 : a3;
            int e4 = half ? b4 : a4, e5 = half ? b5 : a5;
            int e6 = half ? b6 : a6, e7 = half ? b7 : a7;
            unsigned u0 = y[(size_t)e0 * 32 + fl];
            unsigned u1 = y[(size_t)e1 * 32 + fl];
            unsigned u2 = y[(size_t)e2 * 32 + fl];
            unsigned u3 = y[(size_t)e3 * 32 + fl];
            unsigned u4 = y[(size_t)e4 * 32 + fl];
            unsigned u5 = y[(size_t)e5 * 32 + fl];
            unsigned u6 = y[(size_t)e6 * 32 + fl];
            unsigned u7 = y[(size_t)e7 * 32 + fl];
            acc0 += BFLO(u0); acc1 += BFHI(u0);
            acc0 += BFLO(u1); acc1 += BFHI(u1);
            acc0 += BFLO(u2); acc1 += BFHI(u2);
            acc0 += BFLO(u3); acc1 += BFHI(u3);
            acc0 += BFLO(u4); acc1 += BFHI(u4);
            acc0 += BFLO(u5); acc1 += BFHI(u5);
            acc0 += BFLO(u6); acc1 += BFHI(u6);
            acc0 += BFLO(u7); acc1 += BFHI(u7);
        }
        for (; j + 2 <= nb; j += 2) {
            int a = __shfl(idx, j), b = __shfl(idx, j + 1);
            int e = half ? b : a;
            unsigned u = y[(size_t)e * 32 + fl];
            acc0 += BFLO(u); acc1 += BFHI(u);
        }
        if (j < nb) {
            int a = __shfl(idx, j);
            unsigned u = y[(size_t)a * 32 + fl];
            if (!half) { acc0 += BFLO(u); acc1 += BFHI(u); }
        }
    }

    acc0 += __shfl_xor(acc0, 32);
    acc1 += __shfl_xor(acc1, 32);
    if (half == 0) {
        float d = dinv[wid];
        float2 bb = ((const float2*)bias)[fl];
        float2 v;
        v.x = fmaxf(fmaf(acc0, d, bb.x), 0.f);
        v.y = fmaxf(fmaf(acc1, d, bb.y), 0.f);
        ((float2*)hout)[(size_t)wid * 32 + fl] = v;
    }
}

// ---------------- pool (mean per graph, precomputed bounds) + FFN + softmax ----------------
__global__ __launch_bounds__(256) void pool_ffn(const float* __restrict__ h3,
                                                const int* __restrict__ gstart,
                                                const float* __restrict__ Wf,
                                                const float* __restrict__ bf,
                                                float* __restrict__ pooled,
                                                float* __restrict__ ffn,
                                                float* __restrict__ soft)
{
    __shared__ float part[4][64];
    int g = blockIdx.x;
    int t = threadIdx.x, wv = t >> 6, lane = t & 63;
    int start = gstart[g], end = gstart[g + 1];

    float acc = 0.f;
    for (int n = start + wv; n < end; n += 4) acc += h3[(size_t)n * 64 + lane];
    part[wv][lane] = acc;
    __syncthreads();
    if (wv != 0) return;

    float a = part[0][lane] + part[1][lane] + part[2][lane] + part[3][lane];
    float cnt = (float)(end - start);
    float pv = a / fmaxf(cnt, 1.0f);
    pooled[g * 64 + lane] = pv;

    float f = 0.f;
#pragma unroll
    for (int cls = 0; cls < NC; ++cls) {
        float v = pv * Wf[cls * 64 + lane];
#pragma unroll
        for (int off = 32; off; off >>= 1) v += __shfl_xor(v, off);
        if (lane == cls) f = v;
    }
    float fb = (lane < NC) ? fmaxf(f + bf[lane], 0.f) : -INFINITY;
    if (lane < NC) ffn[g * NC + lane] = fb;

    float m = fb;
#pragma unroll
    for (int off = 32; off; off >>= 1) m = fmaxf(m, __shfl_xor(m, off));
    float e = (lane < NC) ? expf(fb - m) : 0.f;
    float s = e;
#pragma unroll
    for (int off = 32; off; off >>= 1) s += __shfl_xor(s, off);
    if (lane < NC) soft[g * NC + lane] = e / s;
}

extern "C" void kernel_launch(void* const* d_in, const int* in_sizes, int n_in,
                              void* d_out, int out_size, void* d_ws, size_t ws_size,
                              hipStream_t stream) {
    const float* x   = (const float*)d_in[0];
    const int*   ei  = (const int*)d_in[1];
    const int*   bat = (const int*)d_in[2];
    const float* W1  = (const float*)d_in[3];
    const float* b1  = (const float*)d_in[4];
    const float* W2  = (const float*)d_in[5];
    const float* b2  = (const float*)d_in[6];
    const float* W3  = (const float*)d_in[7];
    const float* b3  = (const float*)d_in[8];
    const float* Wf  = (const float*)d_in[9];
    const float* bf  = (const float*)d_in[10];

    const int* src = ei;
    const int* dst = ei + NE;

    float* out    = (float*)d_out;
    float* h1     = out;
    float* h2     = out + (size_t)NN * HD;
    float* h3     = out + (size_t)2 * NN * HD;
    float* pooled = out + (size_t)3 * NN * HD;
    float* ffn    = pooled + (size_t)NG * HD;
    float* soft   = ffn + (size_t)NG * NC;

    // workspace layout (bytes):
    //   dinv      [NN f32]        @ 0
    //   rowstart  [NN+1 i32]      @ 400000
    //   srcidx    [NE i32]        @ 800016          (ends 7,200,016)
    //   y         [NN*64 bf16]    @ 7200016         (ends 20,000,016)
    //   gstart    [NG+1 i32]      @ 20000016
    //   -- partition temporaries overlap y (dead before first gemm writes y):
    //   pairs     [NE u32]        @ 7200016
    //   hist      [NB*NBLK i32]   @ 13600016
    //   btotal    [NB i32]        @ 14213104
    //   bucketoff [NB+1 i32]      @ 14216232
    char* ws = (char*)d_ws;
    float*          dinv      = (float*)(ws + 0);
    int*            rowstart  = (int*)(ws + 400000);
    int*            srcidx    = (int*)(ws + 800016);
    unsigned short* y         = (unsigned short*)(ws + 7200016);
    int*            gstart    = (int*)(ws + 20000016);
    unsigned*       pairs     = (unsigned*)(ws + 7200016);
    int*            hist      = (int*)(ws + 13600016);
    int*            btotal    = (int*)(ws + 14213104);
    int*            bucketoff = (int*)(ws + 14216232);

    // ---- edge partition + per-bucket (row,slab) counting sort ----
    hist_buckets<<<NBLK, 256, 0, stream>>>(dst, hist);
    bucket_total<<<(NB + 3) / 4, 256, 0, stream>>>(hist, btotal);
    scan_totals<<<1, 1024, 0, stream>>>(btotal, bucketoff);
    scan_hist<<<(NB + 3) / 4, 256, 0, stream>>>(hist, bucketoff);
    bin_edges<<<NBLK, 256, 0, stream>>>(src, dst, hist, pairs);
    sort_bucket<<<NB, 256, 0, stream>>>(bucketoff, pairs, rowstart, srcidx, dinv);
    graph_bounds<<<(NN + 255) / 256, 256, 0, stream>>>(bat, gstart);

    const int gemmGrid = (NN + 63) / 64;
    const int aggrGrid = (NN + 3) / 4;

    gemm_mfma<<<gemmGrid, 256, 0, stream>>>(x, W1, dinv, y, NN);
    pull_aggr<<<aggrGrid, 256, 0, stream>>>(rowstart, srcidx, (const unsigned*)y, dinv, b1, h1);

    gemm_mfma<<<gemmGrid, 256, 0, stream>>>(h1, W2, dinv, y, NN);
    pull_aggr<<<aggrGrid, 256, 0, stream>>>(rowstart, srcidx, (const unsigned*)y, dinv, b2, h2);

    gemm_mfma<<<gemmGrid, 256, 0, stream>>>(h2, W3, dinv, y, NN);
    pull_aggr<<<aggrGrid, 256, 0, stream>>>(rowstart, srcidx, (const unsigned*)y, dinv, b3, h3);

    pool_ffn<<<NG, 256, 0, stream>>>(h3, gstart, Wf, bf, pooled, ffn, soft);
}

// Round 10
// 286.318 us; speedup vs baseline: 8.4058x; 1.0340x over previous
//
#include <hip/hip_runtime.h>
#include <hip/hip_bf16.h>
#include <math.h>

#define NN 100000      // nodes
#define NE 1600000     // edges
#define HD 64          // feature dim
#define NG 1000        // graphs
#define NC 10          // classes

#define NB 782         // buckets = ceil(NN/128), bucket = dst>>7 (128-node range)
#define NBLK 196       // partition blocks
#define EPB 8164       // edges per partition block = ceil(NE/NBLK)

typedef __attribute__((ext_vector_type(8))) short bf16x8;
typedef __attribute__((ext_vector_type(4))) float f32x4;

__device__ __forceinline__ unsigned short f32_to_bf16(float f) {
    union { float f; unsigned u; } c; c.f = f;
    unsigned u = c.u;
    u += 0x7FFFu + ((u >> 16) & 1u);   // round-to-nearest-even
    return (unsigned short)(u >> 16);
}
#define BFLO(u) __uint_as_float((u) << 16)
#define BFHI(u) __uint_as_float((u) & 0xFFFF0000u)

// ---------------- pass 1a: per-block bucket histogram ----------------
__global__ __launch_bounds__(256) void hist_buckets(const int* __restrict__ dst,
                                                    int* __restrict__ hist)
{
    __shared__ int cnt[NB];
    int t = threadIdx.x, blk = blockIdx.x;
    for (int i = t; i < NB; i += 256) cnt[i] = 0;
    __syncthreads();
    int e0 = blk * EPB;
    int e1 = e0 + EPB; if (e1 > NE) e1 = NE;
    for (int e = e0 + t; e < e1; e += 256) atomicAdd(&cnt[dst[e] >> 7], 1);
    __syncthreads();
    for (int i = t; i < NB; i += 256) hist[(size_t)i * NBLK + blk] = cnt[i];
}

// ---------------- pass 1b: per-bucket totals ----------------
__global__ __launch_bounds__(256) void bucket_total(const int* __restrict__ hist,
                                                    int* __restrict__ btotal)
{
    int w = (blockIdx.x * 256 + threadIdx.x) >> 6;
    int lane = threadIdx.x & 63;
    if (w >= NB) return;
    const int* row = hist + (size_t)w * NBLK;
    int s = 0;
    for (int i = lane; i < NBLK; i += 64) s += row[i];
#pragma unroll
    for (int off = 32; off; off >>= 1) s += __shfl_xor(s, off);
    if (lane == 0) btotal[w] = s;
}

// ---------------- pass 1c: scan bucket totals -> bucketoff ----------------
__global__ __launch_bounds__(1024) void scan_totals(const int* __restrict__ btotal,
                                                    int* __restrict__ bucketoff)
{
    __shared__ int sm[1024];
    int t = threadIdx.x;
    int v = (t < NB) ? btotal[t] : 0;
    sm[t] = v;
    __syncthreads();
    for (int off = 1; off < 1024; off <<= 1) {
        int u = (t >= off) ? sm[t - off] : 0;
        __syncthreads();
        sm[t] += u;
        __syncthreads();
    }
    if (t <= NB) bucketoff[t] = sm[t] - ((t < NB) ? v : 0);
}

// ---------------- pass 1d: hist counts -> global write offsets (in place) ----------------
__global__ __launch_bounds__(256) void scan_hist(int* __restrict__ hist,
                                                 const int* __restrict__ bucketoff)
{
    int w = (blockIdx.x * 256 + threadIdx.x) >> 6;
    int lane = threadIdx.x & 63;
    if (w >= NB) return;
    int run = bucketoff[w];
    int* row = hist + (size_t)w * NBLK;
    for (int c0 = 0; c0 < NBLK; c0 += 64) {
        int idx = c0 + lane;
        int v = (idx < NBLK) ? row[idx] : 0;
        int incl = v;
#pragma unroll
        for (int off = 1; off < 64; off <<= 1) {
            int u = __shfl_up(incl, off);
            if (lane >= off) incl += u;
        }
        if (idx < NBLK) row[idx] = run + incl - v;
        run += __shfl(incl, 63);
    }
}

// ---------------- pass 2: bin edges -> packed pairs (row7|src17), grouped by bucket ----------------
__global__ __launch_bounds__(256) void bin_edges(const int* __restrict__ src,
                                                 const int* __restrict__ dst,
                                                 const int* __restrict__ hist,
                                                 unsigned* __restrict__ pairs)
{
    __shared__ int cur[NB];
    int t = threadIdx.x, blk = blockIdx.x;
    for (int i = t; i < NB; i += 256) cur[i] = hist[(size_t)i * NBLK + blk];
    __syncthreads();
    int e0 = blk * EPB;
    int e1 = e0 + EPB; if (e1 > NE) e1 = NE;
    for (int e = e0 + t; e < e1; e += 256) {
        int d = dst[e], s = src[e];
        int b = d >> 7;
        int pos = atomicAdd(&cur[b], 1);
        pairs[pos] = ((unsigned)(d & 127) << 17) | (unsigned)s;
    }
}

// ---------------- pass 3: per-bucket counting sort -> srcidx (dst-sorted), rowstart, dinv ----------------
__global__ __launch_bounds__(256) void sort_bucket(const int* __restrict__ bucketoff,
                                                   const unsigned* __restrict__ pairs,
                                                   int* __restrict__ rowstart,
                                                   int* __restrict__ srcidx,
                                                   float* __restrict__ dinv)
{
    __shared__ int cnt[128], off[128], cur[128];
    int b = blockIdx.x, t = threadIdx.x;
    int e0 = bucketoff[b], e1 = bucketoff[b + 1];
    if (t < 128) cnt[t] = 0;
    __syncthreads();
    for (int e = e0 + t; e < e1; e += 256) atomicAdd(&cnt[pairs[e] >> 17], 1);
    __syncthreads();
    if (t < 128) off[t] = cnt[t];
    __syncthreads();
    for (int o = 1; o < 128; o <<= 1) {           // Hillis-Steele inclusive scan
        int u = (t < 128 && t >= o) ? off[t - o] : 0;
        __syncthreads();
        if (t < 128) off[t] += u;
        __syncthreads();
    }
    if (t < 128) {
        int ex = e0 + off[t] - cnt[t];            // exclusive + bucket base
        cur[t] = ex;
        int node = (b << 7) + t;
        if (node < NN) {
            rowstart[node] = ex;
            dinv[node] = rsqrtf((float)cnt[t] + 1.0f);
        }
    }
    if (b == NB - 1 && t == 0) rowstart[NN] = e1; // == NE
    __syncthreads();
    for (int e = e0 + t; e < e1; e += 256) {
        unsigned pk = pairs[e];
        int pos = atomicAdd(&cur[pk >> 17], 1);
        srcidx[pos] = (int)(pk & 0x1FFFF);        // block-local contiguous region
    }
}

// ---------------- graph boundaries on sorted batch ----------------
__global__ __launch_bounds__(256) void graph_bounds(const int* __restrict__ batch,
                                                    int* __restrict__ gstart)
{
    int i = blockIdx.x * 256 + threadIdx.x;
    if (i >= NN) return;
    int b = batch[i];
    if (i == 0) {
        for (int g = 0; g <= b; ++g) gstart[g] = 0;
    } else {
        int p = batch[i - 1];
        for (int g = p + 1; g <= b; ++g) gstart[g] = i;
    }
    if (i == NN - 1) {
        for (int g = b + 1; g <= NG; ++g) gstart[g] = NN;
    }
}

// ---------------- per-layer GEMM via MFMA: y = bf16((h @ W^T) * dinv) ----------------
// mfma_f32_16x16x32_bf16. A: lane l -> h[m0+(l&15)][ (l>>4)*8+j ]; B: lane l ->
// W[c*16+(l&15)][ kb*32+(l>>4)*8+j ]; D: col=l&15, row=(l>>4)*4+reg (m89-verified).
__global__ __launch_bounds__(256) void gemm_mfma(const float* __restrict__ h,
                                                 const float* __restrict__ W,
                                                 const float* __restrict__ dinv,
                                                 unsigned short* __restrict__ y,
                                                 int nrows)
{
    const int t = threadIdx.x;
    const int lane = t & 63;
    const int wave = t >> 6;
    const int rbase = blockIdx.x * 64;
    const int l15 = lane & 15;
    const int kq  = lane >> 4;               // 0..3

    bf16x8 Bf[4][2];
#pragma unroll
    for (int c = 0; c < 4; ++c) {
#pragma unroll
        for (int kb = 0; kb < 2; ++kb) {
            const float* wp = W + (c * 16 + l15) * 64 + kb * 32 + kq * 8;
            float f[8];
            *(float4*)(f)     = *(const float4*)(wp);
            *(float4*)(f + 4) = *(const float4*)(wp + 4);
            bf16x8 v;
#pragma unroll
            for (int i = 0; i < 8; ++i) v[i] = (short)f32_to_bf16(f[i]);
            Bf[c][kb] = v;
        }
    }

    int arow = rbase + wave * 16 + l15;
    if (arow >= nrows) arow = nrows - 1;
    bf16x8 Af[2];
#pragma unroll
    for (int kb = 0; kb < 2; ++kb) {
        const float* hp = h + (size_t)arow * 64 + kb * 32 + kq * 8;
        float f[8];
        *(float4*)(f)     = *(const float4*)(hp);
        *(float4*)(f + 4) = *(const float4*)(hp + 4);
        bf16x8 v;
#pragma unroll
        for (int i = 0; i < 8; ++i) v[i] = (short)f32_to_bf16(f[i]);
        Af[kb] = v;
    }

    f32x4 acc[4] = {{0.f,0.f,0.f,0.f},{0.f,0.f,0.f,0.f},{0.f,0.f,0.f,0.f},{0.f,0.f,0.f,0.f}};
#pragma unroll
    for (int c = 0; c < 4; ++c) {
        acc[c] = __builtin_amdgcn_mfma_f32_16x16x32_bf16(Af[0], Bf[c][0], acc[c], 0, 0, 0);
        acc[c] = __builtin_amdgcn_mfma_f32_16x16x32_bf16(Af[1], Bf[c][1], acc[c], 0, 0, 0);
    }

    const int drow0 = rbase + wave * 16 + kq * 4;
#pragma unroll
    for (int r = 0; r < 4; ++r) {
        int rg = drow0 + r;
        if (rg < nrows) {
            float d = dinv[rg];
#pragma unroll
            for (int c = 0; c < 4; ++c)
                y[(size_t)rg * 64 + c * 16 + l15] = f32_to_bf16(acc[c][r] * d);
        }
    }
}

// ---------------- pull aggregation: one node per HALF-WAVE (32 lanes = full 128B row) ----------------
#define NPN 2   // nodes per half-wave (sequential)
__global__ __launch_bounds__(256) void pull_aggr(const int* __restrict__ rowstart,
                                                 const int* __restrict__ srcidx,
                                                 const unsigned* __restrict__ y,   // 32 u32 per row
                                                 const float* __restrict__ dinv,
                                                 const float* __restrict__ bias,
                                                 float* __restrict__ hout)
{
    int hw = (blockIdx.x * blockDim.x + threadIdx.x) >> 5;   // global half-wave id
    int fl = threadIdx.x & 31;
    int hb = threadIdx.x & 32;       // base lane of this half within the 64-lane wave
    float2 bb = ((const float2*)bias)[fl];

#pragma unroll 1
    for (int i = 0; i < NPN; ++i) {
        int n = hw * NPN + i;
        if (n >= NN) return;
        int s0 = rowstart[n], s1 = rowstart[n + 1];
        unsigned su = y[(size_t)n * 32 + fl];          // self-loop term
        float acc0 = BFLO(su), acc1 = BFHI(su);
        for (int base = s0; base < s1; base += 32) {
            int nb = s1 - base; if (nb > 32) nb = 32;
            int idx = (fl < nb) ? srcidx[base + fl] : 0;   // 128B coalesced batch per half
            int j = 0;
            for (; j + 8 <= nb; j += 8) {              // 8 row-gathers in flight per half-wave
                int e0 = __shfl(idx, hb + j + 0), e1 = __shfl(idx, hb + j + 1);
                int e2 = __shfl(idx, hb + j + 2), e3 = __shfl(idx, hb + j + 3);
                int e4 = __shfl(idx, hb + j + 4), e5 = __shfl(idx, hb + j + 5);
                int e6 = __shfl(idx, hb + j + 6), e7 = __shfl(idx, hb + j + 7);
                unsigned u0 = y[(size_t)e0 * 32 + fl];
                unsigned u1 = y[(size_t)e1 * 32 + fl];
                unsigned u2 = y[(size_t)e2 * 32 + fl];
                unsigned u3 = y[(size_t)e3 * 32 + fl];
                unsigned u4 = y[(size_t)e4 * 32 + fl];
                unsigned u5 = y[(size_t)e5 * 32 + fl];
                unsigned u6 = y[(size_t)e6 * 32 + fl];
                unsigned u7 = y[(size_t)e7 * 32 + fl];
                acc0 += BFLO(u0); acc1 += BFHI(u0);
                acc0 += BFLO(u1); acc1 += BFHI(u1);
                acc0 += BFLO(u2); acc1 += BFHI(u2);
                acc0 += BFLO(u3); acc1 += BFHI(u3);
                acc0 += BFLO(u4); acc1 += BFHI(u4);
                acc0 += BFLO(u5); acc1 += BFHI(u5);
                acc0 += BFLO(u6); acc1 += BFHI(u6);
                acc0 += BFLO(u7); acc1 += BFHI(u7);
            }
            for (; j < nb; ++j) {
                int e = __shfl(idx, hb + j);
                unsigned u = y[(size_t)e * 32 + fl];
                acc0 += BFLO(u); acc1 += BFHI(u);
            }
        }
        float d = dinv[n];
        float2 v;
        v.x = fmaxf(fmaf(acc0, d, bb.x), 0.f);
        v.y = fmaxf(fmaf(acc1, d, bb.y), 0.f);
        ((float2*)hout)[(size_t)n * 32 + fl] = v;      // 256B contiguous per half-wave
    }
}

// ---------------- pool (mean per graph, precomputed bounds) + FFN + softmax ----------------
__global__ __launch_bounds__(256) void pool_ffn(const float* __restrict__ h3,
                                                const int* __restrict__ gstart,
                                                const float* __restrict__ Wf,
                                                const float* __restrict__ bf,
                                                float* __restrict__ pooled,
                                                float* __restrict__ ffn,
                                                float* __restrict__ soft)
{
    __shared__ float part[4][64];
    int g = blockIdx.x;
    int t = threadIdx.x, wv = t >> 6, lane = t & 63;
    int start = gstart[g], end = gstart[g + 1];

    float acc = 0.f;
    for (int n = start + wv; n < end; n += 4) acc += h3[(size_t)n * 64 + lane];
    part[wv][lane] = acc;
    __syncthreads();
    if (wv != 0) return;

    float a = part[0][lane] + part[1][lane] + part[2][lane] + part[3][lane];
    float cnt = (float)(end - start);
    float pv = a / fmaxf(cnt, 1.0f);
    pooled[g * 64 + lane] = pv;

    float f = 0.f;
#pragma unroll
    for (int cls = 0; cls < NC; ++cls) {
        float v = pv * Wf[cls * 64 + lane];
#pragma unroll
        for (int off = 32; off; off >>= 1) v += __shfl_xor(v, off);
        if (lane == cls) f = v;
    }
    float fb = (lane < NC) ? fmaxf(f + bf[lane], 0.f) : -INFINITY;
    if (lane < NC) ffn[g * NC + lane] = fb;

    float m = fb;
#pragma unroll
    for (int off = 32; off; off >>= 1) m = fmaxf(m, __shfl_xor(m, off));
    float e = (lane < NC) ? expf(fb - m) : 0.f;
    float s = e;
#pragma unroll
    for (int off = 32; off; off >>= 1) s += __shfl_xor(s, off);
    if (lane < NC) soft[g * NC + lane] = e / s;
}

extern "C" void kernel_launch(void* const* d_in, const int* in_sizes, int n_in,
                              void* d_out, int out_size, void* d_ws, size_t ws_size,
                              hipStream_t stream) {
    const float* x   = (const float*)d_in[0];
    const int*   ei  = (const int*)d_in[1];
    const int*   bat = (const int*)d_in[2];
    const float* W1  = (const float*)d_in[3];
    const float* b1  = (const float*)d_in[4];
    const float* W2  = (const float*)d_in[5];
    const float* b2  = (const float*)d_in[6];
    const float* W3  = (const float*)d_in[7];
    const float* b3  = (const float*)d_in[8];
    const float* Wf  = (const float*)d_in[9];
    const float* bf  = (const float*)d_in[10];

    const int* src = ei;
    const int* dst = ei + NE;

    float* out    = (float*)d_out;
    float* h1     = out;
    float* h2     = out + (size_t)NN * HD;
    float* h3     = out + (size_t)2 * NN * HD;
    float* pooled = out + (size_t)3 * NN * HD;
    float* ffn    = pooled + (size_t)NG * HD;
    float* soft   = ffn + (size_t)NG * NC;

    // workspace layout (bytes):
    //   dinv      [NN f32]        @ 0
    //   rowstart  [NN+1 i32]      @ 400000
    //   srcidx    [NE i32]        @ 800016          (ends 7,200,016)
    //   y         [NN*64 bf16]    @ 7200016         (ends 20,000,016)
    //   gstart    [NG+1 i32]      @ 20000016
    //   -- partition temporaries overlap y (dead before first gemm writes y):
    //   pairs     [NE u32]        @ 7200016
    //   hist      [NB*NBLK i32]   @ 13600016
    //   btotal    [NB i32]        @ 14213104
    //   bucketoff [NB+1 i32]      @ 14216232
    char* ws = (char*)d_ws;
    float*          dinv      = (float*)(ws + 0);
    int*            rowstart  = (int*)(ws + 400000);
    int*            srcidx    = (int*)(ws + 800016);
    unsigned short* y         = (unsigned short*)(ws + 7200016);
    int*            gstart    = (int*)(ws + 20000016);
    unsigned*       pairs     = (unsigned*)(ws + 7200016);
    int*            hist      = (int*)(ws + 13600016);
    int*            btotal    = (int*)(ws + 14213104);
    int*            bucketoff = (int*)(ws + 14216232);

    // ---- edge partition + per-bucket counting sort (amortized across 3 layers) ----
    hist_buckets<<<NBLK, 256, 0, stream>>>(dst, hist);
    bucket_total<<<(NB + 3) / 4, 256, 0, stream>>>(hist, btotal);
    scan_totals<<<1, 1024, 0, stream>>>(btotal, bucketoff);
    scan_hist<<<(NB + 3) / 4, 256, 0, stream>>>(hist, bucketoff);
    bin_edges<<<NBLK, 256, 0, stream>>>(src, dst, hist, pairs);
    sort_bucket<<<NB, 256, 0, stream>>>(bucketoff, pairs, rowstart, srcidx, dinv);
    graph_bounds<<<(NN + 255) / 256, 256, 0, stream>>>(bat, gstart);

    const int gemmGrid = (NN + 63) / 64;
    const int aggrGrid = (NN + 8 * NPN - 1) / (8 * NPN);   // 8 half-waves/block, NPN nodes each

    gemm_mfma<<<gemmGrid, 256, 0, stream>>>(x, W1, dinv, y, NN);
    pull_aggr<<<aggrGrid, 256, 0, stream>>>(rowstart, srcidx, (const unsigned*)y, dinv, b1, h1);

    gemm_mfma<<<gemmGrid, 256, 0, stream>>>(h1, W2, dinv, y, NN);
    pull_aggr<<<aggrGrid, 256, 0, stream>>>(rowstart, srcidx, (const unsigned*)y, dinv, b2, h2);

    gemm_mfma<<<gemmGrid, 256, 0, stream>>>(h2, W3, dinv, y, NN);
    pull_aggr<<<aggrGrid, 256, 0, stream>>>(rowstart, srcidx, (const unsigned*)y, dinv, b3, h3);

    pool_ffn<<<NG, 256, 0, stream>>>(h3, gstart, Wf, bf, pooled, ffn, soft);
}